// Round 9
// baseline (231.984 us; speedup 1.0000x reference)
//
#include <hip/hip_runtime.h>

// ANCF recommender on MI355X.
// prep (MFMA hidden -> Khid bf16; keys^T -> Vpan bf16 n-panels; colsum partials)
//  -> sreduceA/B (S = colsum, 2-stage tree)
//  -> flash (streaming softmax attention, 32x32x16 MFMA, swapped QK^T,
//            exp2 with log2e folded into Q, in-register P via cvt_pk+permlane32_swap;
//            K/V staged via global_load_lds into DOUBLE-buffered LDS (32 KB);
//            4-WAVE blocks: unified VGPR+AGPR ~92/wave caps the CU at ~22 waves,
//            so 256-thread blocks give 5 resident blocks = 20 waves/CU vs 2x512=16.
//            DMA issued one full phase ahead; raw s_barrier; vmcnt waits are on
//            phase-old loads. No min-waves launch bound (round-7 spill lesson).)
//  -> combine (O/l, q2, epilogue (q2+S)W1^T+(q2*S)W2^T, leaky_relu, build og)
//  -> final1/2 (128x128 = og_user^T @ og_item, LDS-tiled, 32-way k-split)
// Workspace required: ~95 MB.

typedef __bf16 bf16x8 __attribute__((ext_vector_type(8)));
typedef float f32x4 __attribute__((ext_vector_type(4)));
typedef float f32x16 __attribute__((ext_vector_type(16)));
typedef unsigned int u32x4 __attribute__((ext_vector_type(4)));

static constexpr int NKEYS  = 100000;
static constexpr int NP     = 102400;          // 64 chunks * 1600 rows
static constexpr int DIM    = 64;
static constexpr int BQ     = 2048;
static constexpr int NCH    = 64;
static constexpr int CHROWS = NP / NCH;        // 1600
static constexpr int NPH    = CHROWS / 64;     // 25 phases of 64 n
static constexpr int NTIL   = NP / 64;         // 1600
static constexpr float PADCNT = float(NP - NKEYS);   // 2400: each pad adds exp2(0)=1 to l
static constexpr float LOG2E  = 1.44269504088896340736f;

#define DEVINL __device__ __forceinline__

DEVINL unsigned int cvtpk(float lo, float hi) {
    unsigned int r;
    asm("v_cvt_pk_bf16_f32 %0, %1, %2" : "=v"(r) : "v"(lo), "v"(hi));
    return r;
}
DEVINL unsigned short bfr(float f) {           // single f32 -> bf16 (RNE)
    return (unsigned short)(cvtpk(f, f) & 0xffffu);
}
DEVINL float bf2f(unsigned short u) {
    unsigned int w = (unsigned int)u << 16;
    return __builtin_bit_cast(float, w);
}
DEVINL void permswap(unsigned int& a, unsigned int& b) {
    asm("v_permlane32_swap_b32 %0, %1" : "+v"(a), "+v"(b));
}
DEVINL bf16x8 pack_frag(unsigned int w0, unsigned int w1, unsigned int w2, unsigned int w3) {
    u32x4 t; t[0] = w0; t[1] = w1; t[2] = w2; t[3] = w3;
    return __builtin_bit_cast(bf16x8, t);
}
DEVINL bf16x8 frag8_f32(const float* p) {      // 8 consecutive f32 -> bf16x8 frag
    f32x4 a = *reinterpret_cast<const f32x4*>(p);
    f32x4 b = *reinterpret_cast<const f32x4*>(p + 4);
    return pack_frag(cvtpk(a[0], a[1]), cvtpk(a[2], a[3]),
                     cvtpk(b[0], b[1]), cvtpk(b[2], b[3]));
}
// async global -> LDS DMA, 16B per lane; LDS dest = wave-uniform base + lane*16
DEVINL void gl_lds16(const void* g, void* l) {
    __builtin_amdgcn_global_load_lds(
        (const __attribute__((address_space(1))) unsigned int*)g,
        (__attribute__((address_space(3))) unsigned int*)l, 16, 0, 0);
}

// ---------------------------------------------------------------------------
// prep: per 64-row tile: hidden = relu(K @ aW^T + b) via 32x32x16 MFMA -> Khid bf16;
//       K^T -> Vpan bf16 (n-panels: Vpan[n/32][64 d][32 nn], each panel 4KB contiguous);
//       column-sum partials. Pad rows (n >= NKEYS) exact zeros.
// grid (NTIL, 2), block 256
// ---------------------------------------------------------------------------
__global__ __launch_bounds__(256) void prep_kernel(
    const float* __restrict__ user_emb, const float* __restrict__ item_emb,
    const float* __restrict__ uaW, const float* __restrict__ uab,
    const float* __restrict__ iaW, const float* __restrict__ iab,
    unsigned short* __restrict__ Khid, unsigned short* __restrict__ Vpan,
    float* __restrict__ csum)
{
    const int side = blockIdx.y;
    const int tile = blockIdx.x;
    const float* keys = (side == 0) ? item_emb : user_emb;
    const float* aW   = (side == 0) ? uaW : iaW;
    const float* ab   = (side == 0) ? uab : iab;
    unsigned short* Kh  = Khid + (size_t)side * NP * DIM;
    unsigned short* Vps = Vpan + (size_t)side * (NP / 32) * 2048;

    __shared__ float Kf[64][68];
    __shared__ float Wf[64][68];
    __shared__ float bl[64];

    const int t  = threadIdx.x;
    const int r  = t >> 2;
    const int c0 = (t & 3) * 16;

    {   // stage aW rows (f32)
        const float4* src = reinterpret_cast<const float4*>(aW + r * 64 + c0);
        float4* dst = reinterpret_cast<float4*>(&Wf[r][c0]);
        #pragma unroll
        for (int q = 0; q < 4; ++q) dst[q] = src[q];
        if (t < 64) bl[t] = ab[t];
    }
    {   // stage keys tile (zero pads)
        const int n = tile * 64 + r;
        float4* dst = reinterpret_cast<float4*>(&Kf[r][c0]);
        if (n < NKEYS) {
            const float4* src = reinterpret_cast<const float4*>(keys + (size_t)n * 64 + c0);
            #pragma unroll
            for (int q = 0; q < 4; ++q) dst[q] = src[q];
        } else {
            const float4 z = make_float4(0.f, 0.f, 0.f, 0.f);
            #pragma unroll
            for (int q = 0; q < 4; ++q) dst[q] = z;
        }
    }
    __syncthreads();

    {   // hidden 32x32 tile per wave via MFMA; frag convention identical to flash QK^T
        const int wv = t >> 6, lane = t & 63;
        const int c = lane & 31, hi = lane >> 5;
        const int n0 = (wv & 1) * 32, j0 = (wv >> 1) * 32;
        f32x16 acc{};
        #pragma unroll
        for (int ks = 0; ks < 4; ++ks) {
            bf16x8 af = frag8_f32(&Kf[n0 + c][ks * 16 + hi * 8]);
            bf16x8 bf_ = frag8_f32(&Wf[j0 + c][ks * 16 + hi * 8]);
            acc = __builtin_amdgcn_mfma_f32_32x32x16_bf16(af, bf_, acc, 0, 0, 0);
        }
        const float bj = bl[j0 + c];
        #pragma unroll
        for (int rr = 0; rr < 16; ++rr) {
            const int n  = n0 + (rr & 3) + 8 * (rr >> 2) + 4 * hi;
            const int gn = tile * 64 + n;
            float h = fmaxf(acc[rr] + bj, 0.f);
            if (gn >= NKEYS) h = 0.f;
            Kh[(size_t)gn * 64 + j0 + c] = bfr(h);
        }
    }
    {   // Vpan: thread: d = r, nn-cols c0..c0+15 within this 64-tile (2 panels per tile)
        unsigned int pw[8];
        #pragma unroll
        for (int j = 0; j < 8; ++j)
            pw[j] = cvtpk(Kf[c0 + 2 * j][r], Kf[c0 + 2 * j + 1][r]);
        unsigned short* dst = Vps + ((size_t)(2 * tile + (c0 >> 5))) * 2048 + r * 32 + (c0 & 31);
        uint4* d4 = reinterpret_cast<uint4*>(dst);
        d4[0] = make_uint4(pw[0], pw[1], pw[2], pw[3]);
        d4[1] = make_uint4(pw[4], pw[5], pw[6], pw[7]);
    }
    if (t < 64) {   // column partial sums (f32, exact keys)
        float s = 0.f;
        #pragma unroll 8
        for (int rr = 0; rr < 64; ++rr) s += Kf[rr][t];
        csum[((size_t)side * NTIL + tile) * 64 + t] = s;
    }
}

// grid (64, 2), block 64: csum2[side][j][d] = sum_{idx=j mod 64} csum[side][idx][d]
__global__ __launch_bounds__(64) void sreduceA_kernel(const float* __restrict__ csum,
                                                      float* __restrict__ csum2)
{
    const int j = blockIdx.x, side = blockIdx.y, d = threadIdx.x;
    float s = 0.f;
    for (int idx = j; idx < NTIL; idx += 64)
        s += csum[((size_t)side * NTIL + idx) * 64 + d];
    csum2[((size_t)side * 64 + j) * 64 + d] = s;
}

// grid (2), block 64
__global__ __launch_bounds__(64) void sreduceB_kernel(const float* __restrict__ csum2,
                                                      float* __restrict__ Sbuf)
{
    const int side = blockIdx.x, d = threadIdx.x;
    float s = 0.f;
    #pragma unroll 8
    for (int j = 0; j < 64; ++j) s += csum2[((size_t)side * 64 + j) * 64 + d];
    Sbuf[side * 64 + d] = s;
}

// ---------------------------------------------------------------------------
// flash: block = 4 waves (256 thr), each wave a 32-query tile; block covers 128 q
//        over one n-chunk of 1600 keys, in 25 phases of 64 n.
// Staging: per phase 16KB (K 8KB + V 8KB) via global_load_lds, 4 issues/wave:
//   wave 0/1 -> K subtile st=wave (issue j = k-step, src stride 32B);
//   wave 2/3 -> V panel  st=wave-2 (issue j = (ns,hi), src stride 16B).
//   DOUBLE-buffered (2 x 16KB LDS = 32 KB). DMA for p+1 issued at top of phase p;
//   pre-barrier vmcnt(0) waits on phase-old loads. Raw s_barrier.
// LDS per buffer (shorts): K: st*2048 + ks*512 + hi*256 + c*8  (K[st*32+c][16ks+8hi..+7])
//                          V: 4096 + st*2048 + ns*1024 + hi*512 + dblk*256 + c*8
//                             (V[st*32+16ns+8hi+j][32dblk+c])
// Swapped QK^T: S^T = mfma(A=K, B=Q^T); C/D: col=lane&31=q, row=(r&3)+8*(r>>2)+4*hi=n.
// P = exp2(S) (Q pre-scaled by log2e; scores bounded, no max-sub).
// grid (NCH, 16, 2) = 2048 blocks; ~5 blocks/CU resident (regs 22-wave cap / 4).
// ---------------------------------------------------------------------------
__global__ __launch_bounds__(256) void flash_kernel(
    const float* __restrict__ user_emb, const float* __restrict__ item_emb,
    const int* __restrict__ user_id, const int* __restrict__ item_id,
    const unsigned short* __restrict__ Khid, const unsigned short* __restrict__ Vpan,
    unsigned short* __restrict__ Opart, float* __restrict__ lpart)
{
    const int side  = blockIdx.z;
    const int chunk = blockIdx.x;
    const int qblk  = blockIdx.y;
    const int wave  = threadIdx.x >> 6;
    const int lane  = threadIdx.x & 63;
    const int c  = lane & 31;
    const int hi = lane >> 5;

    __shared__ __align__(16) unsigned short KV[2][8192];   // 2 x 16KB

    const float* emb = (side == 0) ? user_emb : item_emb;
    const int* ids   = (side == 0) ? user_id  : item_id;
    const unsigned short* Kh = Khid + (size_t)side * NP * DIM + (size_t)chunk * CHROWS * DIM;
    const unsigned short* Vb = Vpan + ((size_t)side * (NP / 32) + (size_t)chunk * (CHROWS / 32)) * 2048;

    // ---- staging setup: wave w stages LDS shorts [w*2048, w*2048+2048) per phase,
    //      4 DMA issues of 1KB (lane*16B), source contiguous-permuted in global.
    const char* gsrc;
    int jstep;
    if (wave < 2) {
        // K subtile st=wave: global byte (st*32+c')*128 + (2ks+hi')*16
        gsrc = (const char*)Kh + wave * 4096
             + (lane & 31) * 128 + (lane >> 5) * 16;
        jstep = 32;      // ks stride
    } else {
        // V panel st=wave-2: global byte panel + lane*64 + ns*32 + hi*16
        gsrc = (const char*)Vb + (wave - 2) * 4096 + lane * 64;
        jstep = 16;      // (ns,hi) stride
    }
    unsigned short* const lbase = &KV[0][0] + wave * 2048;

    const char* gnext = gsrc;               // source cursor for next ISSUE
    int ibuf = 0;                           // LDS buffer for next ISSUE
    auto ISSUE = [&]() {
        unsigned short* l = lbase + ibuf * 8192;
        gl_lds16(gnext, l);
        gl_lds16(gnext + jstep,     l + 512);
        gl_lds16(gnext + 2 * jstep, l + 1024);
        gl_lds16(gnext + 3 * jstep, l + 1536);
        gnext += 8192;
        ibuf ^= 1;
    };

    // ---- Q gather
    const int qtile = qblk * 128 + wave * 32;
    const int id = ids[qtile + c];
    const float* qrow = emb + (size_t)id * 64 + hi * 8;
    float4 qf[8];
    #pragma unroll
    for (int ds = 0; ds < 4; ++ds) {
        qf[2 * ds]     = *reinterpret_cast<const float4*>(qrow + ds * 16);
        qf[2 * ds + 1] = *reinterpret_cast<const float4*>(qrow + ds * 16 + 4);
    }

    ISSUE();            // phase 0 -> buf 0

    // pack Q (B-operand of swapped QK^T), scaled by log2(e)
    bf16x8 bq[4];
    #pragma unroll
    for (int ds = 0; ds < 4; ++ds)
        bq[ds] = pack_frag(cvtpk(qf[2 * ds].x * LOG2E, qf[2 * ds].y * LOG2E),
                           cvtpk(qf[2 * ds].z * LOG2E, qf[2 * ds].w * LOG2E),
                           cvtpk(qf[2 * ds + 1].x * LOG2E, qf[2 * ds + 1].y * LOG2E),
                           cvtpk(qf[2 * ds + 1].z * LOG2E, qf[2 * ds + 1].w * LOG2E));

    f32x16 o0{}, o1{};
    f32x4 lsv{};

    asm volatile("s_waitcnt vmcnt(0)" ::: "memory");   // phase-0 DMA done
    __builtin_amdgcn_s_barrier();

    for (int p = 0; p < NPH; ++p) {
        // issue DMA for phase p+1 into buf (p+1)&1 -- that buffer's readers all
        // passed the barrier that just released us, so the overwrite is safe.
        if (p + 1 < NPH) ISSUE();

        const unsigned short* Bp = &KV[p & 1][0];
        #pragma unroll
        for (int st = 0; st < 2; ++st) {
            const int kb = st * 2048 + hi * 256 + c * 8;   // shorts
            bf16x8 ak0 = *reinterpret_cast<const bf16x8*>(&Bp[kb]);
            bf16x8 ak1 = *reinterpret_cast<const bf16x8*>(&Bp[kb + 512]);
            bf16x8 ak2 = *reinterpret_cast<const bf16x8*>(&Bp[kb + 1024]);
            bf16x8 ak3 = *reinterpret_cast<const bf16x8*>(&Bp[kb + 1536]);

            __builtin_amdgcn_s_setprio(1);
            f32x16 s{};
            s = __builtin_amdgcn_mfma_f32_32x32x16_bf16(ak0, bq[0], s, 0, 0, 0);
            s = __builtin_amdgcn_mfma_f32_32x32x16_bf16(ak1, bq[1], s, 0, 0, 0);
            s = __builtin_amdgcn_mfma_f32_32x32x16_bf16(ak2, bq[2], s, 0, 0, 0);
            s = __builtin_amdgcn_mfma_f32_32x32x16_bf16(ak3, bq[3], s, 0, 0, 0);
            __builtin_amdgcn_s_setprio(0);

            const int vb = 4096 + st * 2048 + hi * 512 + c * 8;   // shorts
            bf16x8 v00 = *reinterpret_cast<const bf16x8*>(&Bp[vb]);           // ns0 dblk0
            bf16x8 v01 = *reinterpret_cast<const bf16x8*>(&Bp[vb + 256]);     // ns0 dblk1
            bf16x8 v10 = *reinterpret_cast<const bf16x8*>(&Bp[vb + 1024]);    // ns1 dblk0
            bf16x8 v11 = *reinterpret_cast<const bf16x8*>(&Bp[vb + 1280]);    // ns1 dblk1

            #pragma unroll
            for (int rr = 0; rr < 16; ++rr) s[rr] = __builtin_exp2f(s[rr]);
            #pragma unroll
            for (int rr = 0; rr < 16; ++rr) lsv[rr & 3] += s[rr];

            unsigned int w0 = cvtpk(s[0], s[1]),  w2 = cvtpk(s[4], s[5]);
            permswap(w0, w2);
            unsigned int w1 = cvtpk(s[2], s[3]),  w3 = cvtpk(s[6], s[7]);
            permswap(w1, w3);
            bf16x8 a0 = pack_frag(w0, w1, w2, w3);
            unsigned int x0 = cvtpk(s[8], s[9]),   x2 = cvtpk(s[12], s[13]);
            permswap(x0, x2);
            unsigned int x1 = cvtpk(s[10], s[11]), x3 = cvtpk(s[14], s[15]);
            permswap(x1, x3);
            bf16x8 a1 = pack_frag(x0, x1, x2, x3);

            __builtin_amdgcn_s_setprio(1);
            o0 = __builtin_amdgcn_mfma_f32_32x32x16_bf16(a0, v00, o0, 0, 0, 0);
            o0 = __builtin_amdgcn_mfma_f32_32x32x16_bf16(a1, v10, o0, 0, 0, 0);
            o1 = __builtin_amdgcn_mfma_f32_32x32x16_bf16(a0, v01, o1, 0, 0, 0);
            o1 = __builtin_amdgcn_mfma_f32_32x32x16_bf16(a1, v11, o1, 0, 0, 0);
            __builtin_amdgcn_s_setprio(0);
        }

        if (p + 1 < NPH) {
            // own 4 DMAs for p+1 were issued a full phase ago -> near-free wait
            asm volatile("s_waitcnt vmcnt(0)" ::: "memory");
            __builtin_amdgcn_s_barrier();
        }
    }

    float ls = lsv[0] + lsv[1] + lsv[2] + lsv[3];
    ls += __shfl_xor(ls, 32);   // lane c now holds l[qtile+c] for this chunk

    unsigned short* Op = Opart + (((size_t)(side * NCH + chunk)) * BQ + qtile) * 64;
    #pragma unroll
    for (int rr = 0; rr < 16; ++rr) {
        const int q = (rr & 3) + 8 * (rr >> 2) + 4 * hi;
        Op[q * 64 + c]      = bfr(o0[rr]);
        Op[q * 64 + 32 + c] = bfr(o1[rr]);
    }
    if (hi == 0)
        lpart[((size_t)(side * NCH + chunk)) * BQ + qtile + c] = ls;
}

// ---------------------------------------------------------------------------
// combine: O = sum(Opart)/(sum(lpart) - PADCNT); q2 = e + O;
//          out = leaky_relu((q2+S)@W1^T + (q2*S)@W2^T); og = [e, out]
// grid (2*BQ), block 64
// ---------------------------------------------------------------------------
__global__ __launch_bounds__(64) void combine_kernel(
    const float* __restrict__ user_emb, const float* __restrict__ item_emb,
    const int* __restrict__ user_id, const int* __restrict__ item_id,
    const float* __restrict__ uW1, const float* __restrict__ uW2,
    const float* __restrict__ iW1, const float* __restrict__ iW2,
    const unsigned short* __restrict__ Opart, const float* __restrict__ lpart,
    const float* __restrict__ Sbuf,
    float* __restrict__ Aog, float* __restrict__ Bog)
{
    const int bid  = blockIdx.x;
    const int side = bid >> 11;
    const int q    = bid & (BQ - 1);
    const int d    = threadIdx.x;

    const unsigned short* Ob = Opart + ((size_t)side * NCH * BQ + q) * 64 + d;
    float num = 0.f;
    #pragma unroll 8
    for (int ch = 0; ch < NCH; ++ch)
        num += bf2f(Ob[(size_t)ch * BQ * 64]);
    const float* lb = lpart + (size_t)side * NCH * BQ + q;
    float lsum = -PADCNT;
    #pragma unroll 8
    for (int ch = 0; ch < NCH; ++ch)
        lsum += lb[(size_t)ch * BQ];

    const int id = ((side == 0) ? user_id : item_id)[q];
    const float* emb = (side == 0) ? user_emb : item_emb;
    const float e  = emb[(size_t)id * 64 + d];
    const float q2 = e + num / lsum;
    const float Sd = Sbuf[side * 64 + d];

    __shared__ float a1[64], a2[64];
    a1[d] = q2 + Sd;
    a2[d] = q2 * Sd;
    __syncthreads();

    const float* W1 = (side == 0) ? uW1 : iW1;
    const float* W2 = (side == 0) ? uW2 : iW2;
    float acc = 0.f;
    #pragma unroll 8
    for (int dd = 0; dd < 64; ++dd)
        acc += a1[dd] * W1[d * 64 + dd] + a2[dd] * W2[d * 64 + dd];
    const float out = (acc >= 0.f) ? acc : 0.01f * acc;

    float* og = (side == 0) ? Aog : Bog;
    og[(size_t)q * 128 + d]      = e;
    og[(size_t)q * 128 + 64 + d] = out;
}

// final stage 1: grid 32, block 256; block b: t-rows [64b, 64b+64), LDS-tiled,
// partial[b][i][j] = sum_t Aog[t][i]*Bog[t][j]
__global__ __launch_bounds__(256) void final1_kernel(
    const float* __restrict__ Aog, const float* __restrict__ Bog, float* __restrict__ part)
{
    const int b = blockIdx.x;
    const int t = threadIdx.x;
    __shared__ float As[64][128];
    __shared__ float Bs[64][128];
    {
        float* Asf = &As[0][0];
        float* Bsf = &Bs[0][0];
        const float* Ab = Aog + (size_t)b * 64 * 128;
        const float* Bb = Bog + (size_t)b * 64 * 128;
        #pragma unroll
        for (int qq = 0; qq < 8; ++qq) {
            const int off = qq * 1024 + t * 4;
            *reinterpret_cast<float4*>(Asf + off) = *reinterpret_cast<const float4*>(Ab + off);
            *reinterpret_cast<float4*>(Bsf + off) = *reinterpret_cast<const float4*>(Bb + off);
        }
    }
    __syncthreads();

    const int i0 = (t >> 4) * 8, j0 = (t & 15) * 8;
    float acc[8][8] = {};
    for (int k = 0; k < 64; ++k) {
        float av[8], bv[8];
        *reinterpret_cast<f32x4*>(&av[0]) = *reinterpret_cast<const f32x4*>(&As[k][i0]);
        *reinterpret_cast<f32x4*>(&av[4]) = *reinterpret_cast<const f32x4*>(&As[k][i0 + 4]);
        *reinterpret_cast<f32x4*>(&bv[0]) = *reinterpret_cast<const f32x4*>(&Bs[k][j0]);
        *reinterpret_cast<f32x4*>(&bv[4]) = *reinterpret_cast<const f32x4*>(&Bs[k][j0 + 4]);
        #pragma unroll
        for (int ii = 0; ii < 8; ++ii)
            #pragma unroll
            for (int jj = 0; jj < 8; ++jj)
                acc[ii][jj] += av[ii] * bv[jj];
    }
    float* P = part + (size_t)b * 128 * 128;
    #pragma unroll
    for (int ii = 0; ii < 8; ++ii) {
        *reinterpret_cast<float4*>(P + (i0 + ii) * 128 + j0)     = *reinterpret_cast<float4*>(&acc[ii][0]);
        *reinterpret_cast<float4*>(P + (i0 + ii) * 128 + j0 + 4) = *reinterpret_cast<float4*>(&acc[ii][4]);
    }
}

// final stage 2: grid 128, block 128: out[i][j] = sum_b partial[b][i][j]
__global__ __launch_bounds__(128) void final2_kernel(const float* __restrict__ part,
                                                     float* __restrict__ out)
{
    const int i = blockIdx.x, j = threadIdx.x;
    float s = 0.f;
    #pragma unroll 8
    for (int b = 0; b < 32; ++b) s += part[(size_t)b * 128 * 128 + i * 128 + j];
    out[i * 128 + j] = s;
}

extern "C" void kernel_launch(void* const* d_in, const int* in_sizes, int n_in,
                              void* d_out, int out_size, void* d_ws, size_t ws_size,
                              hipStream_t stream)
{
    (void)in_sizes; (void)n_in; (void)out_size; (void)ws_size;
    const float* user_emb = (const float*)d_in[0];
    const float* item_emb = (const float*)d_in[1];
    const float* uaW = (const float*)d_in[2];
    const float* uab = (const float*)d_in[3];
    const float* uW1 = (const float*)d_in[4];
    const float* uW2 = (const float*)d_in[5];
    const float* iaW = (const float*)d_in[6];
    const float* iab = (const float*)d_in[7];
    const float* iW1 = (const float*)d_in[8];
    const float* iW2 = (const float*)d_in[9];
    const int* user_id = (const int*)d_in[10];
    const int* item_id = (const int*)d_in[11];
    // d_in[12], d_in[13]: arange identity gathers -- no-ops.

    char* ws = (char*)d_ws;
    size_t off = 0;
    auto alloc = [&](size_t bytes) -> void* {
        void* p = ws + off;
        off = (off + bytes + 255) & ~(size_t)255;
        return p;
    };
    unsigned short* Khid = (unsigned short*)alloc((size_t)2 * NP * DIM * 2);
    unsigned short* Vpan = (unsigned short*)alloc((size_t)2 * (NP / 32) * 2048 * 2);
    float* csum  = (float*)alloc((size_t)2 * NTIL * 64 * 4);
    float* csum2 = (float*)alloc((size_t)2 * 64 * 64 * 4);
    float* Sbuf  = (float*)alloc((size_t)2 * 64 * 4);
    unsigned short* Opart = (unsigned short*)alloc((size_t)2 * NCH * BQ * 64 * 2);
    float* lpart = (float*)alloc((size_t)2 * NCH * BQ * 4);
    float* Aog   = (float*)alloc((size_t)BQ * 128 * 4);
    float* Bog   = (float*)alloc((size_t)BQ * 128 * 4);
    float* Fpart = (float*)alloc((size_t)32 * 128 * 128 * 4);

    prep_kernel<<<dim3(NTIL, 2), 256, 0, stream>>>(user_emb, item_emb, uaW, uab, iaW, iab,
                                                   Khid, Vpan, csum);
    sreduceA_kernel<<<dim3(64, 2), 64, 0, stream>>>(csum, csum2);
    sreduceB_kernel<<<2, 64, 0, stream>>>(csum2, Sbuf);
    flash_kernel<<<dim3(NCH, BQ / 128, 2), 256, 0, stream>>>(user_emb, item_emb, user_id, item_id,
                                                             Khid, Vpan, Opart, lpart);
    combine_kernel<<<2 * BQ, 64, 0, stream>>>(user_emb, item_emb, user_id, item_id,
                                              uW1, uW2, iW1, iW2, Opart, lpart, Sbuf, Aog, Bog);
    final1_kernel<<<32, 256, 0, stream>>>(Aog, Bog, Fpart);
    final2_kernel<<<128, 128, 0, stream>>>(Fpart, (float*)d_out);
}

// Round 10
// 224.723 us; speedup vs baseline: 1.0323x; 1.0323x over previous
//
#include <hip/hip_runtime.h>

// ANCF recommender on MI355X.
// prep (MFMA hidden -> Khid bf16; keys^T -> Vpan bf16 n-panels; colsum partials)
//  -> sreduceA/B (S = colsum, 2-stage tree)
//  -> flash (streaming softmax attention, 32x32x16 MFMA, swapped QK^T,
//            exp2 with log2e folded into Q, in-register P via cvt_pk+permlane32_swap;
//            K/V staged via global_load_lds into DOUBLE-buffered LDS (32 KB);
//            4-wave blocks, **64 q per wave (2 q-tiles)** so each LDS K/V fragment
//            read feeds 2 MFMAs -- halves the LDS-read floor (R9 analysis: each
//            wave reading the whole 16KB buffer was a 64 us/CU issue floor).
//            DMA issued one full phase ahead; raw s_barrier. No min-waves bound.)
//  -> combine (O/l, q2, epilogue (q2+S)W1^T+(q2*S)W2^T, leaky_relu, build og)
//  -> final1/2 (128x128 = og_user^T @ og_item, LDS-tiled, 32-way k-split)
// Workspace required: ~95 MB.

typedef __bf16 bf16x8 __attribute__((ext_vector_type(8)));
typedef float f32x4 __attribute__((ext_vector_type(4)));
typedef float f32x16 __attribute__((ext_vector_type(16)));
typedef unsigned int u32x4 __attribute__((ext_vector_type(4)));

static constexpr int NKEYS  = 100000;
static constexpr int NP     = 102400;          // 64 chunks * 1600 rows
static constexpr int DIM    = 64;
static constexpr int BQ     = 2048;
static constexpr int NCH    = 64;
static constexpr int CHROWS = NP / NCH;        // 1600
static constexpr int NPH    = CHROWS / 64;     // 25 phases of 64 n
static constexpr int NTIL   = NP / 64;         // 1600
static constexpr float PADCNT = float(NP - NKEYS);   // 2400: each pad adds exp2(0)=1 to l
static constexpr float LOG2E  = 1.44269504088896340736f;

#define DEVINL __device__ __forceinline__

DEVINL unsigned int cvtpk(float lo, float hi) {
    unsigned int r;
    asm("v_cvt_pk_bf16_f32 %0, %1, %2" : "=v"(r) : "v"(lo), "v"(hi));
    return r;
}
DEVINL unsigned short bfr(float f) {           // single f32 -> bf16 (RNE)
    return (unsigned short)(cvtpk(f, f) & 0xffffu);
}
DEVINL float bf2f(unsigned short u) {
    unsigned int w = (unsigned int)u << 16;
    return __builtin_bit_cast(float, w);
}
DEVINL void permswap(unsigned int& a, unsigned int& b) {
    asm("v_permlane32_swap_b32 %0, %1" : "+v"(a), "+v"(b));
}
DEVINL bf16x8 pack_frag(unsigned int w0, unsigned int w1, unsigned int w2, unsigned int w3) {
    u32x4 t; t[0] = w0; t[1] = w1; t[2] = w2; t[3] = w3;
    return __builtin_bit_cast(bf16x8, t);
}
DEVINL bf16x8 frag8_f32(const float* p) {      // 8 consecutive f32 -> bf16x8 frag
    f32x4 a = *reinterpret_cast<const f32x4*>(p);
    f32x4 b = *reinterpret_cast<const f32x4*>(p + 4);
    return pack_frag(cvtpk(a[0], a[1]), cvtpk(a[2], a[3]),
                     cvtpk(b[0], b[1]), cvtpk(b[2], b[3]));
}
// async global -> LDS DMA, 16B per lane; LDS dest = wave-uniform base + lane*16
DEVINL void gl_lds16(const void* g, void* l) {
    __builtin_amdgcn_global_load_lds(
        (const __attribute__((address_space(1))) unsigned int*)g,
        (__attribute__((address_space(3))) unsigned int*)l, 16, 0, 0);
}

// ---------------------------------------------------------------------------
// prep: per 64-row tile: hidden = relu(K @ aW^T + b) via 32x32x16 MFMA -> Khid bf16;
//       K^T -> Vpan bf16 (n-panels: Vpan[n/32][64 d][32 nn], each panel 4KB contiguous);
//       column-sum partials. Pad rows (n >= NKEYS) exact zeros.
// grid (NTIL, 2), block 256
// ---------------------------------------------------------------------------
__global__ __launch_bounds__(256) void prep_kernel(
    const float* __restrict__ user_emb, const float* __restrict__ item_emb,
    const float* __restrict__ uaW, const float* __restrict__ uab,
    const float* __restrict__ iaW, const float* __restrict__ iab,
    unsigned short* __restrict__ Khid, unsigned short* __restrict__ Vpan,
    float* __restrict__ csum)
{
    const int side = blockIdx.y;
    const int tile = blockIdx.x;
    const float* keys = (side == 0) ? item_emb : user_emb;
    const float* aW   = (side == 0) ? uaW : iaW;
    const float* ab   = (side == 0) ? uab : iab;
    unsigned short* Kh  = Khid + (size_t)side * NP * DIM;
    unsigned short* Vps = Vpan + (size_t)side * (NP / 32) * 2048;

    __shared__ float Kf[64][68];
    __shared__ float Wf[64][68];
    __shared__ float bl[64];

    const int t  = threadIdx.x;
    const int r  = t >> 2;
    const int c0 = (t & 3) * 16;

    {   // stage aW rows (f32)
        const float4* src = reinterpret_cast<const float4*>(aW + r * 64 + c0);
        float4* dst = reinterpret_cast<float4*>(&Wf[r][c0]);
        #pragma unroll
        for (int q = 0; q < 4; ++q) dst[q] = src[q];
        if (t < 64) bl[t] = ab[t];
    }
    {   // stage keys tile (zero pads)
        const int n = tile * 64 + r;
        float4* dst = reinterpret_cast<float4*>(&Kf[r][c0]);
        if (n < NKEYS) {
            const float4* src = reinterpret_cast<const float4*>(keys + (size_t)n * 64 + c0);
            #pragma unroll
            for (int q = 0; q < 4; ++q) dst[q] = src[q];
        } else {
            const float4 z = make_float4(0.f, 0.f, 0.f, 0.f);
            #pragma unroll
            for (int q = 0; q < 4; ++q) dst[q] = z;
        }
    }
    __syncthreads();

    {   // hidden 32x32 tile per wave via MFMA; frag convention identical to flash QK^T
        const int wv = t >> 6, lane = t & 63;
        const int c = lane & 31, hi = lane >> 5;
        const int n0 = (wv & 1) * 32, j0 = (wv >> 1) * 32;
        f32x16 acc{};
        #pragma unroll
        for (int ks = 0; ks < 4; ++ks) {
            bf16x8 af = frag8_f32(&Kf[n0 + c][ks * 16 + hi * 8]);
            bf16x8 bf_ = frag8_f32(&Wf[j0 + c][ks * 16 + hi * 8]);
            acc = __builtin_amdgcn_mfma_f32_32x32x16_bf16(af, bf_, acc, 0, 0, 0);
        }
        const float bj = bl[j0 + c];
        #pragma unroll
        for (int rr = 0; rr < 16; ++rr) {
            const int n  = n0 + (rr & 3) + 8 * (rr >> 2) + 4 * hi;
            const int gn = tile * 64 + n;
            float h = fmaxf(acc[rr] + bj, 0.f);
            if (gn >= NKEYS) h = 0.f;
            Kh[(size_t)gn * 64 + j0 + c] = bfr(h);
        }
    }
    {   // Vpan: thread: d = r, nn-cols c0..c0+15 within this 64-tile (2 panels per tile)
        unsigned int pw[8];
        #pragma unroll
        for (int j = 0; j < 8; ++j)
            pw[j] = cvtpk(Kf[c0 + 2 * j][r], Kf[c0 + 2 * j + 1][r]);
        unsigned short* dst = Vps + ((size_t)(2 * tile + (c0 >> 5))) * 2048 + r * 32 + (c0 & 31);
        uint4* d4 = reinterpret_cast<uint4*>(dst);
        d4[0] = make_uint4(pw[0], pw[1], pw[2], pw[3]);
        d4[1] = make_uint4(pw[4], pw[5], pw[6], pw[7]);
    }
    if (t < 64) {   // column partial sums (f32, exact keys)
        float s = 0.f;
        #pragma unroll 8
        for (int rr = 0; rr < 64; ++rr) s += Kf[rr][t];
        csum[((size_t)side * NTIL + tile) * 64 + t] = s;
    }
}

// grid (64, 2), block 64: csum2[side][j][d] = sum_{idx=j mod 64} csum[side][idx][d]
__global__ __launch_bounds__(64) void sreduceA_kernel(const float* __restrict__ csum,
                                                      float* __restrict__ csum2)
{
    const int j = blockIdx.x, side = blockIdx.y, d = threadIdx.x;
    float s = 0.f;
    for (int idx = j; idx < NTIL; idx += 64)
        s += csum[((size_t)side * NTIL + idx) * 64 + d];
    csum2[((size_t)side * 64 + j) * 64 + d] = s;
}

// grid (2), block 64
__global__ __launch_bounds__(64) void sreduceB_kernel(const float* __restrict__ csum2,
                                                      float* __restrict__ Sbuf)
{
    const int side = blockIdx.x, d = threadIdx.x;
    float s = 0.f;
    #pragma unroll 8
    for (int j = 0; j < 64; ++j) s += csum2[((size_t)side * 64 + j) * 64 + d];
    Sbuf[side * 64 + d] = s;
}

// ---------------------------------------------------------------------------
// flash: block = 4 waves (256 thr); each wave owns TWO 32-query tiles (64 q),
//        block covers 256 q over one n-chunk of 1600 keys, 25 phases of 64 n.
// Each K fragment read feeds QK for both q-tiles; each V fragment read feeds
// PV for both q-tiles -> LDS-read instructions per MFMA halved vs 1-tile/wave.
// Staging (as round 9, correctness-proven): per phase 16KB via global_load_lds,
//   4 issues/wave; wave 0/1 -> K subtile st=wave; wave 2/3 -> V panel st=wave-2.
//   DOUBLE-buffered (2 x 16KB). DMA for p+1 issued at top of phase p; the
//   pre-barrier vmcnt(0) waits on phase-old loads. Raw s_barrier.
// LDS per buffer (shorts): K: st*2048 + ks*512 + hi*256 + c*8  (K[st*32+c][16ks+8hi..+7])
//                          V: 4096 + st*2048 + ns*1024 + hi*512 + dblk*256 + c*8
// Swapped QK^T: S^T = mfma(A=K, B=Q^T); C/D: col=lane&31=q, row=(r&3)+8*(r>>2)+4*hi=n.
// P = exp2(S) (Q pre-scaled by log2e; scores bounded, no max-sub).
// grid (NCH, 8, 2) = 1024 blocks, 4 blocks/CU of work, ~3 resident (reg-capped).
// ---------------------------------------------------------------------------
__global__ __launch_bounds__(256) void flash_kernel(
    const float* __restrict__ user_emb, const float* __restrict__ item_emb,
    const int* __restrict__ user_id, const int* __restrict__ item_id,
    const unsigned short* __restrict__ Khid, const unsigned short* __restrict__ Vpan,
    unsigned short* __restrict__ Opart, float* __restrict__ lpart)
{
    const int side  = blockIdx.z;
    const int chunk = blockIdx.x;
    const int qblk  = blockIdx.y;
    const int wave  = threadIdx.x >> 6;
    const int lane  = threadIdx.x & 63;
    const int c  = lane & 31;
    const int hi = lane >> 5;

    __shared__ __align__(16) unsigned short KV[2][8192];   // 2 x 16KB

    const float* emb = (side == 0) ? user_emb : item_emb;
    const int* ids   = (side == 0) ? user_id  : item_id;
    const unsigned short* Kh = Khid + (size_t)side * NP * DIM + (size_t)chunk * CHROWS * DIM;
    const unsigned short* Vb = Vpan + ((size_t)side * (NP / 32) + (size_t)chunk * (CHROWS / 32)) * 2048;

    // ---- staging setup: wave w stages LDS shorts [w*2048, w*2048+2048) per phase,
    //      4 DMA issues of 1KB (lane*16B), source contiguous-permuted in global.
    const char* gsrc;
    int jstep;
    if (wave < 2) {
        // K subtile st=wave: global byte (st*32+c')*128 + (2ks+hi')*16
        gsrc = (const char*)Kh + wave * 4096
             + (lane & 31) * 128 + (lane >> 5) * 16;
        jstep = 32;      // ks stride
    } else {
        // V panel st=wave-2: global byte panel + lane*64 + ns*32 + hi*16
        gsrc = (const char*)Vb + (wave - 2) * 4096 + lane * 64;
        jstep = 16;      // (ns,hi) stride
    }
    unsigned short* const lbase = &KV[0][0] + wave * 2048;

    const char* gnext = gsrc;               // source cursor for next ISSUE
    int ibuf = 0;                           // LDS buffer for next ISSUE
    auto ISSUE = [&]() {
        unsigned short* l = lbase + ibuf * 8192;
        gl_lds16(gnext, l);
        gl_lds16(gnext + jstep,     l + 512);
        gl_lds16(gnext + 2 * jstep, l + 1024);
        gl_lds16(gnext + 3 * jstep, l + 1536);
        gnext += 8192;
        ibuf ^= 1;
    };

    ISSUE();            // phase 0 -> buf 0 (in flight during Q gather/pack)

    // ---- Q gather + pack, two q-tiles per wave (B-operand of swapped QK^T), *log2e
    const int qtile = qblk * 256 + wave * 64;
    bf16x8 bq0[4], bq1[4];
    #pragma unroll
    for (int tl = 0; tl < 2; ++tl) {
        const int id = ids[qtile + tl * 32 + c];
        const float* qrow = emb + (size_t)id * 64 + hi * 8;
        bf16x8* bq = tl ? bq1 : bq0;
        #pragma unroll
        for (int ds = 0; ds < 4; ++ds) {
            float4 f0 = *reinterpret_cast<const float4*>(qrow + ds * 16);
            float4 f1 = *reinterpret_cast<const float4*>(qrow + ds * 16 + 4);
            bq[ds] = pack_frag(cvtpk(f0.x * LOG2E, f0.y * LOG2E),
                               cvtpk(f0.z * LOG2E, f0.w * LOG2E),
                               cvtpk(f1.x * LOG2E, f1.y * LOG2E),
                               cvtpk(f1.z * LOG2E, f1.w * LOG2E));
        }
    }

    f32x16 o00{}, o01{}, o10{}, o11{};
    f32x4 lsv0{}, lsv1{};

    asm volatile("s_waitcnt vmcnt(0)" ::: "memory");   // phase-0 DMA done
    __builtin_amdgcn_s_barrier();

    for (int p = 0; p < NPH; ++p) {
        if (p + 1 < NPH) ISSUE();

        const unsigned short* Bp = &KV[p & 1][0];
        #pragma unroll
        for (int st = 0; st < 2; ++st) {
            const int kb = st * 2048 + hi * 256 + c * 8;   // shorts
            bf16x8 ak0 = *reinterpret_cast<const bf16x8*>(&Bp[kb]);
            bf16x8 ak1 = *reinterpret_cast<const bf16x8*>(&Bp[kb + 512]);
            bf16x8 ak2 = *reinterpret_cast<const bf16x8*>(&Bp[kb + 1024]);
            bf16x8 ak3 = *reinterpret_cast<const bf16x8*>(&Bp[kb + 1536]);

            __builtin_amdgcn_s_setprio(1);
            f32x16 s0{}, s1{};
            s0 = __builtin_amdgcn_mfma_f32_32x32x16_bf16(ak0, bq0[0], s0, 0, 0, 0);
            s1 = __builtin_amdgcn_mfma_f32_32x32x16_bf16(ak0, bq1[0], s1, 0, 0, 0);
            s0 = __builtin_amdgcn_mfma_f32_32x32x16_bf16(ak1, bq0[1], s0, 0, 0, 0);
            s1 = __builtin_amdgcn_mfma_f32_32x32x16_bf16(ak1, bq1[1], s1, 0, 0, 0);
            s0 = __builtin_amdgcn_mfma_f32_32x32x16_bf16(ak2, bq0[2], s0, 0, 0, 0);
            s1 = __builtin_amdgcn_mfma_f32_32x32x16_bf16(ak2, bq1[2], s1, 0, 0, 0);
            s0 = __builtin_amdgcn_mfma_f32_32x32x16_bf16(ak3, bq0[3], s0, 0, 0, 0);
            s1 = __builtin_amdgcn_mfma_f32_32x32x16_bf16(ak3, bq1[3], s1, 0, 0, 0);
            __builtin_amdgcn_s_setprio(0);

            const int vb = 4096 + st * 2048 + hi * 512 + c * 8;   // shorts
            bf16x8 v00 = *reinterpret_cast<const bf16x8*>(&Bp[vb]);           // ns0 dblk0
            bf16x8 v01 = *reinterpret_cast<const bf16x8*>(&Bp[vb + 256]);     // ns0 dblk1
            bf16x8 v10 = *reinterpret_cast<const bf16x8*>(&Bp[vb + 1024]);    // ns1 dblk0
            bf16x8 v11 = *reinterpret_cast<const bf16x8*>(&Bp[vb + 1280]);    // ns1 dblk1

            // ---- tile 0 softmax + PV
            #pragma unroll
            for (int rr = 0; rr < 16; ++rr) s0[rr] = __builtin_exp2f(s0[rr]);
            #pragma unroll
            for (int rr = 0; rr < 16; ++rr) lsv0[rr & 3] += s0[rr];
            {
                unsigned int w0 = cvtpk(s0[0], s0[1]),  w2 = cvtpk(s0[4], s0[5]);
                permswap(w0, w2);
                unsigned int w1 = cvtpk(s0[2], s0[3]),  w3 = cvtpk(s0[6], s0[7]);
                permswap(w1, w3);
                bf16x8 a0 = pack_frag(w0, w1, w2, w3);
                unsigned int x0 = cvtpk(s0[8], s0[9]),   x2 = cvtpk(s0[12], s0[13]);
                permswap(x0, x2);
                unsigned int x1 = cvtpk(s0[10], s0[11]), x3 = cvtpk(s0[14], s0[15]);
                permswap(x1, x3);
                bf16x8 a1 = pack_frag(x0, x1, x2, x3);

                __builtin_amdgcn_s_setprio(1);
                o00 = __builtin_amdgcn_mfma_f32_32x32x16_bf16(a0, v00, o00, 0, 0, 0);
                o00 = __builtin_amdgcn_mfma_f32_32x32x16_bf16(a1, v10, o00, 0, 0, 0);
                o01 = __builtin_amdgcn_mfma_f32_32x32x16_bf16(a0, v01, o01, 0, 0, 0);
                o01 = __builtin_amdgcn_mfma_f32_32x32x16_bf16(a1, v11, o01, 0, 0, 0);
                __builtin_amdgcn_s_setprio(0);
            }
            // ---- tile 1 softmax + PV
            #pragma unroll
            for (int rr = 0; rr < 16; ++rr) s1[rr] = __builtin_exp2f(s1[rr]);
            #pragma unroll
            for (int rr = 0; rr < 16; ++rr) lsv1[rr & 3] += s1[rr];
            {
                unsigned int w0 = cvtpk(s1[0], s1[1]),  w2 = cvtpk(s1[4], s1[5]);
                permswap(w0, w2);
                unsigned int w1 = cvtpk(s1[2], s1[3]),  w3 = cvtpk(s1[6], s1[7]);
                permswap(w1, w3);
                bf16x8 a0 = pack_frag(w0, w1, w2, w3);
                unsigned int x0 = cvtpk(s1[8], s1[9]),   x2 = cvtpk(s1[12], s1[13]);
                permswap(x0, x2);
                unsigned int x1 = cvtpk(s1[10], s1[11]), x3 = cvtpk(s1[14], s1[15]);
                permswap(x1, x3);
                bf16x8 a1 = pack_frag(x0, x1, x2, x3);

                __builtin_amdgcn_s_setprio(1);
                o10 = __builtin_amdgcn_mfma_f32_32x32x16_bf16(a0, v00, o10, 0, 0, 0);
                o10 = __builtin_amdgcn_mfma_f32_32x32x16_bf16(a1, v10, o10, 0, 0, 0);
                o11 = __builtin_amdgcn_mfma_f32_32x32x16_bf16(a0, v01, o11, 0, 0, 0);
                o11 = __builtin_amdgcn_mfma_f32_32x32x16_bf16(a1, v11, o11, 0, 0, 0);
                __builtin_amdgcn_s_setprio(0);
            }
        }

        if (p + 1 < NPH) {
            // own 4 DMAs for p+1 were issued a full phase ago -> near-free wait
            asm volatile("s_waitcnt vmcnt(0)" ::: "memory");
            __builtin_amdgcn_s_barrier();
        }
    }

    float ls0 = lsv0[0] + lsv0[1] + lsv0[2] + lsv0[3];
    float ls1 = lsv1[0] + lsv1[1] + lsv1[2] + lsv1[3];
    ls0 += __shfl_xor(ls0, 32);
    ls1 += __shfl_xor(ls1, 32);

    unsigned short* Op0 = Opart + (((size_t)(side * NCH + chunk)) * BQ + qtile) * 64;
    unsigned short* Op1 = Op0 + 32 * 64;
    #pragma unroll
    for (int rr = 0; rr < 16; ++rr) {
        const int q = (rr & 3) + 8 * (rr >> 2) + 4 * hi;
        Op0[q * 64 + c]      = bfr(o00[rr]);
        Op0[q * 64 + 32 + c] = bfr(o01[rr]);
        Op1[q * 64 + c]      = bfr(o10[rr]);
        Op1[q * 64 + 32 + c] = bfr(o11[rr]);
    }
    if (hi == 0) {
        lpart[((size_t)(side * NCH + chunk)) * BQ + qtile + c]      = ls0;
        lpart[((size_t)(side * NCH + chunk)) * BQ + qtile + 32 + c] = ls1;
    }
}

// ---------------------------------------------------------------------------
// combine: O = sum(Opart)/(sum(lpart) - PADCNT); q2 = e + O;
//          out = leaky_relu((q2+S)@W1^T + (q2*S)@W2^T); og = [e, out]
// grid (2*BQ), block 64
// ---------------------------------------------------------------------------
__global__ __launch_bounds__(64) void combine_kernel(
    const float* __restrict__ user_emb, const float* __restrict__ item_emb,
    const int* __restrict__ user_id, const int* __restrict__ item_id,
    const float* __restrict__ uW1, const float* __restrict__ uW2,
    const float* __restrict__ iW1, const float* __restrict__ iW2,
    const unsigned short* __restrict__ Opart, const float* __restrict__ lpart,
    const float* __restrict__ Sbuf,
    float* __restrict__ Aog, float* __restrict__ Bog)
{
    const int bid  = blockIdx.x;
    const int side = bid >> 11;
    const int q    = bid & (BQ - 1);
    const int d    = threadIdx.x;

    const unsigned short* Ob = Opart + ((size_t)side * NCH * BQ + q) * 64 + d;
    float num = 0.f;
    #pragma unroll 8
    for (int ch = 0; ch < NCH; ++ch)
        num += bf2f(Ob[(size_t)ch * BQ * 64]);
    const float* lb = lpart + (size_t)side * NCH * BQ + q;
    float lsum = -PADCNT;
    #pragma unroll 8
    for (int ch = 0; ch < NCH; ++ch)
        lsum += lb[(size_t)ch * BQ];

    const int id = ((side == 0) ? user_id : item_id)[q];
    const float* emb = (side == 0) ? user_emb : item_emb;
    const float e  = emb[(size_t)id * 64 + d];
    const float q2 = e + num / lsum;
    const float Sd = Sbuf[side * 64 + d];

    __shared__ float a1[64], a2[64];
    a1[d] = q2 + Sd;
    a2[d] = q2 * Sd;
    __syncthreads();

    const float* W1 = (side == 0) ? uW1 : iW1;
    const float* W2 = (side == 0) ? uW2 : iW2;
    float acc = 0.f;
    #pragma unroll 8
    for (int dd = 0; dd < 64; ++dd)
        acc += a1[dd] * W1[d * 64 + dd] + a2[dd] * W2[d * 64 + dd];
    const float out = (acc >= 0.f) ? acc : 0.01f * acc;

    float* og = (side == 0) ? Aog : Bog;
    og[(size_t)q * 128 + d]      = e;
    og[(size_t)q * 128 + 64 + d] = out;
}

// final stage 1: grid 32, block 256; block b: t-rows [64b, 64b+64), LDS-tiled,
// partial[b][i][j] = sum_t Aog[t][i]*Bog[t][j]
__global__ __launch_bounds__(256) void final1_kernel(
    const float* __restrict__ Aog, const float* __restrict__ Bog, float* __restrict__ part)
{
    const int b = blockIdx.x;
    const int t = threadIdx.x;
    __shared__ float As[64][128];
    __shared__ float Bs[64][128];
    {
        float* Asf = &As[0][0];
        float* Bsf = &Bs[0][0];
        const float* Ab = Aog + (size_t)b * 64 * 128;
        const float* Bb = Bog + (size_t)b * 64 * 128;
        #pragma unroll
        for (int qq = 0; qq < 8; ++qq) {
            const int off = qq * 1024 + t * 4;
            *reinterpret_cast<float4*>(Asf + off) = *reinterpret_cast<const float4*>(Ab + off);
            *reinterpret_cast<float4*>(Bsf + off) = *reinterpret_cast<const float4*>(Bb + off);
        }
    }
    __syncthreads();

    const int i0 = (t >> 4) * 8, j0 = (t & 15) * 8;
    float acc[8][8] = {};
    for (int k = 0; k < 64; ++k) {
        float av[8], bv[8];
        *reinterpret_cast<f32x4*>(&av[0]) = *reinterpret_cast<const f32x4*>(&As[k][i0]);
        *reinterpret_cast<f32x4*>(&av[4]) = *reinterpret_cast<const f32x4*>(&As[k][i0 + 4]);
        *reinterpret_cast<f32x4*>(&bv[0]) = *reinterpret_cast<const f32x4*>(&Bs[k][j0]);
        *reinterpret_cast<f32x4*>(&bv[4]) = *reinterpret_cast<const f32x4*>(&Bs[k][j0 + 4]);
        #pragma unroll
        for (int ii = 0; ii < 8; ++ii)
            #pragma unroll
            for (int jj = 0; jj < 8; ++jj)
                acc[ii][jj] += av[ii] * bv[jj];
    }
    float* P = part + (size_t)b * 128 * 128;
    #pragma unroll
    for (int ii = 0; ii < 8; ++ii) {
        *reinterpret_cast<float4*>(P + (i0 + ii) * 128 + j0)     = *reinterpret_cast<float4*>(&acc[ii][0]);
        *reinterpret_cast<float4*>(P + (i0 + ii) * 128 + j0 + 4) = *reinterpret_cast<float4*>(&acc[ii][4]);
    }
}

// final stage 2: grid 128, block 128: out[i][j] = sum_b partial[b][i][j]
__global__ __launch_bounds__(128) void final2_kernel(const float* __restrict__ part,
                                                     float* __restrict__ out)
{
    const int i = blockIdx.x, j = threadIdx.x;
    float s = 0.f;
    #pragma unroll 8
    for (int b = 0; b < 32; ++b) s += part[(size_t)b * 128 * 128 + i * 128 + j];
    out[i * 128 + j] = s;
}

extern "C" void kernel_launch(void* const* d_in, const int* in_sizes, int n_in,
                              void* d_out, int out_size, void* d_ws, size_t ws_size,
                              hipStream_t stream)
{
    (void)in_sizes; (void)n_in; (void)out_size; (void)ws_size;
    const float* user_emb = (const float*)d_in[0];
    const float* item_emb = (const float*)d_in[1];
    const float* uaW = (const float*)d_in[2];
    const float* uab = (const float*)d_in[3];
    const float* uW1 = (const float*)d_in[4];
    const float* uW2 = (const float*)d_in[5];
    const float* iaW = (const float*)d_in[6];
    const float* iab = (const float*)d_in[7];
    const float* iW1 = (const float*)d_in[8];
    const float* iW2 = (const float*)d_in[9];
    const int* user_id = (const int*)d_in[10];
    const int* item_id = (const int*)d_in[11];
    // d_in[12], d_in[13]: arange identity gathers -- no-ops.

    char* ws = (char*)d_ws;
    size_t off = 0;
    auto alloc = [&](size_t bytes) -> void* {
        void* p = ws + off;
        off = (off + bytes + 255) & ~(size_t)255;
        return p;
    };
    unsigned short* Khid = (unsigned short*)alloc((size_t)2 * NP * DIM * 2);
    unsigned short* Vpan = (unsigned short*)alloc((size_t)2 * (NP / 32) * 2048 * 2);
    float* csum  = (float*)alloc((size_t)2 * NTIL * 64 * 4);
    float* csum2 = (float*)alloc((size_t)2 * 64 * 64 * 4);
    float* Sbuf  = (float*)alloc((size_t)2 * 64 * 4);
    unsigned short* Opart = (unsigned short*)alloc((size_t)2 * NCH * BQ * 64 * 2);
    float* lpart = (float*)alloc((size_t)2 * NCH * BQ * 4);
    float* Aog   = (float*)alloc((size_t)BQ * 128 * 4);
    float* Bog   = (float*)alloc((size_t)BQ * 128 * 4);
    float* Fpart = (float*)alloc((size_t)32 * 128 * 128 * 4);

    prep_kernel<<<dim3(NTIL, 2), 256, 0, stream>>>(user_emb, item_emb, uaW, uab, iaW, iab,
                                                   Khid, Vpan, csum);
    sreduceA_kernel<<<dim3(64, 2), 64, 0, stream>>>(csum, csum2);
    sreduceB_kernel<<<2, 64, 0, stream>>>(csum2, Sbuf);
    flash_kernel<<<dim3(NCH, BQ / 256, 2), 256, 0, stream>>>(user_emb, item_emb, user_id, item_id,
                                                             Khid, Vpan, Opart, lpart);
    combine_kernel<<<2 * BQ, 64, 0, stream>>>(user_emb, item_emb, user_id, item_id,
                                              uW1, uW2, iW1, iW2, Opart, lpart, Sbuf, Aog, Bog);
    final1_kernel<<<32, 256, 0, stream>>>(Aog, Bog, Fpart);
    final2_kernel<<<128, 128, 0, stream>>>(Fpart, (float*)d_out);
}

// Round 11
// 185.720 us; speedup vs baseline: 1.2491x; 1.2100x over previous
//
#include <hip/hip_runtime.h>

// ANCF recommender on MI355X.
// prep (MFMA hidden -> Khid fp8; keys^T -> Vpan fp8 n-panels; colsum partials)
//  -> sreduceA/B (S = colsum, 2-stage tree)
//  -> flash (streaming softmax attention, MX-fp8 mfma_scale 32x32x64 (scales=1.0):
//            QK^T = 1 MFMA per 32-n subtile (K=64 = full d), PV = 1 MFMA per d-half
//            (K=64 = full phase-n). 4 MFMA + 8 ds_read_b128 per wave-phase vs
//            16 + 16 for the bf16 32x32x16 version (R8, 157 us plateau).
//            P built in-register: 16 cvt_pk_fp8 + 4 permlane32_swap.
//            K/V staged via global_load_lds, double-buffered 2x8KB, 1 DMA/wave/phase,
//            DMA one full phase ahead; raw s_barrier. 8-wave blocks (R8 skeleton).)
//  -> combine (O/l, q2, epilogue (q2+S)W1^T+(q2*S)W2^T, leaky_relu, build og)
//  -> final1/2 (128x128 = og_user^T @ og_item, LDS-tiled, 32-way k-split)
// Workspace required: ~70 MB.

typedef __bf16 bf16x8 __attribute__((ext_vector_type(8)));
typedef float f32x4 __attribute__((ext_vector_type(4)));
typedef float f32x16 __attribute__((ext_vector_type(16)));
typedef unsigned int u32x4 __attribute__((ext_vector_type(4)));
typedef int i32x4 __attribute__((ext_vector_type(4)));
typedef int i32x8 __attribute__((ext_vector_type(8)));

static constexpr int NKEYS  = 100000;
static constexpr int NP     = 102400;          // 64 chunks * 1600 rows
static constexpr int DIM    = 64;
static constexpr int BQ     = 2048;
static constexpr int NCH    = 64;
static constexpr int CHROWS = NP / NCH;        // 1600
static constexpr int NPH    = CHROWS / 64;     // 25 phases of 64 n
static constexpr int NTIL   = NP / 64;         // 1600
static constexpr float PADCNT = float(NP - NKEYS);   // 2400: each pad adds exp2(0)=1 to l
static constexpr float LOG2E  = 1.44269504088896340736f;

#define DEVINL __device__ __forceinline__

DEVINL unsigned int cvtpk(float lo, float hi) {
    unsigned int r;
    asm("v_cvt_pk_bf16_f32 %0, %1, %2" : "=v"(r) : "v"(lo), "v"(hi));
    return r;
}
DEVINL unsigned short bfr(float f) {           // single f32 -> bf16 (RNE)
    return (unsigned short)(cvtpk(f, f) & 0xffffu);
}
DEVINL float bf2f(unsigned short u) {
    unsigned int w = (unsigned int)u << 16;
    return __builtin_bit_cast(float, w);
}
DEVINL void permswap(unsigned int& a, unsigned int& b) {
    asm("v_permlane32_swap_b32 %0, %1" : "+v"(a), "+v"(b));
}
DEVINL bf16x8 pack_frag(unsigned int w0, unsigned int w1, unsigned int w2, unsigned int w3) {
    u32x4 t; t[0] = w0; t[1] = w1; t[2] = w2; t[3] = w3;
    return __builtin_bit_cast(bf16x8, t);
}
DEVINL bf16x8 frag8_f32(const float* p) {      // 8 consecutive f32 -> bf16x8 frag
    f32x4 a = *reinterpret_cast<const f32x4*>(p);
    f32x4 b = *reinterpret_cast<const f32x4*>(p + 4);
    return pack_frag(cvtpk(a[0], a[1]), cvtpk(a[2], a[3]),
                     cvtpk(b[0], b[1]), cvtpk(b[2], b[3]));
}
// fp8 e4m3 helpers
DEVINL unsigned int fp8x4(float a, float b, float c, float d) {
    int r = __builtin_amdgcn_cvt_pk_fp8_f32(a, b, 0, false);   // bytes 0,1
    r = __builtin_amdgcn_cvt_pk_fp8_f32(c, d, r, true);        // bytes 2,3
    return (unsigned int)r;
}
DEVINL unsigned char fp8b(float f) {
    return (unsigned char)(__builtin_amdgcn_cvt_pk_fp8_f32(f, f, 0, false) & 0xFF);
}
DEVINL i32x8 cat8(i32x4 a, i32x4 b) {
    return __builtin_shufflevector(a, b, 0, 1, 2, 3, 4, 5, 6, 7);
}
// fp8 e4m3 MFMA, K=64, scales = 1.0 (e8m0 = 127 in every byte)
DEVINL f32x16 mfma8(i32x8 a, i32x8 b, f32x16 c) {
    return __builtin_amdgcn_mfma_scale_f32_32x32x64_f8f6f4(
        a, b, c, 0 /*cbsz: fp8*/, 0 /*blgp: fp8*/,
        0, 0x7F7F7F7F, 0, 0x7F7F7F7F);
}
// async global -> LDS DMA, 16B per lane; LDS dest = wave-uniform base + lane*16
DEVINL void gl_lds16(const void* g, void* l) {
    __builtin_amdgcn_global_load_lds(
        (const __attribute__((address_space(1))) unsigned int*)g,
        (__attribute__((address_space(3))) unsigned int*)l, 16, 0, 0);
}

// ---------------------------------------------------------------------------
// prep: per 64-row tile: hidden = relu(K @ aW^T + b) via 32x32x16 bf16 MFMA
//       -> Khid fp8 [n][64]; K^T -> Vpan fp8 (panels: Vpan[n/32][64 d][32 nn],
//       each panel 2KB contiguous); column-sum partials (f32, exact).
//       Pad rows (n >= NKEYS) exact zeros.
// grid (NTIL, 2), block 256
// ---------------------------------------------------------------------------
__global__ __launch_bounds__(256) void prep_kernel(
    const float* __restrict__ user_emb, const float* __restrict__ item_emb,
    const float* __restrict__ uaW, const float* __restrict__ uab,
    const float* __restrict__ iaW, const float* __restrict__ iab,
    unsigned char* __restrict__ Khid, unsigned char* __restrict__ Vpan,
    float* __restrict__ csum)
{
    const int side = blockIdx.y;
    const int tile = blockIdx.x;
    const float* keys = (side == 0) ? item_emb : user_emb;
    const float* aW   = (side == 0) ? uaW : iaW;
    const float* ab   = (side == 0) ? uab : iab;
    unsigned char* Kh  = Khid + (size_t)side * NP * DIM;
    unsigned char* Vps = Vpan + (size_t)side * (NP / 32) * 2048;

    __shared__ float Kf[64][68];
    __shared__ float Wf[64][68];
    __shared__ float bl[64];

    const int t  = threadIdx.x;
    const int r  = t >> 2;
    const int c0 = (t & 3) * 16;

    {   // stage aW rows (f32)
        const float4* src = reinterpret_cast<const float4*>(aW + r * 64 + c0);
        float4* dst = reinterpret_cast<float4*>(&Wf[r][c0]);
        #pragma unroll
        for (int q = 0; q < 4; ++q) dst[q] = src[q];
        if (t < 64) bl[t] = ab[t];
    }
    {   // stage keys tile (zero pads)
        const int n = tile * 64 + r;
        float4* dst = reinterpret_cast<float4*>(&Kf[r][c0]);
        if (n < NKEYS) {
            const float4* src = reinterpret_cast<const float4*>(keys + (size_t)n * 64 + c0);
            #pragma unroll
            for (int q = 0; q < 4; ++q) dst[q] = src[q];
        } else {
            const float4 z = make_float4(0.f, 0.f, 0.f, 0.f);
            #pragma unroll
            for (int q = 0; q < 4; ++q) dst[q] = z;
        }
    }
    __syncthreads();

    {   // hidden 32x32 tile per wave via bf16 MFMA
        const int wv = t >> 6, lane = t & 63;
        const int c = lane & 31, hi = lane >> 5;
        const int n0 = (wv & 1) * 32, j0 = (wv >> 1) * 32;
        f32x16 acc{};
        #pragma unroll
        for (int ks = 0; ks < 4; ++ks) {
            bf16x8 af = frag8_f32(&Kf[n0 + c][ks * 16 + hi * 8]);
            bf16x8 bf_ = frag8_f32(&Wf[j0 + c][ks * 16 + hi * 8]);
            acc = __builtin_amdgcn_mfma_f32_32x32x16_bf16(af, bf_, acc, 0, 0, 0);
        }
        const float bj = bl[j0 + c];
        #pragma unroll
        for (int rr = 0; rr < 16; ++rr) {
            const int n  = n0 + (rr & 3) + 8 * (rr >> 2) + 4 * hi;
            const int gn = tile * 64 + n;
            float h = fmaxf(acc[rr] + bj, 0.f);
            if (gn >= NKEYS) h = 0.f;
            Kh[(size_t)gn * 64 + j0 + c] = fp8b(h);
        }
    }
    {   // Vpan fp8: thread: d = r, nn-cols c0..c0+15 within this 64-tile
        unsigned int pw[4];
        #pragma unroll
        for (int j = 0; j < 4; ++j)
            pw[j] = fp8x4(Kf[c0 + 4 * j][r],     Kf[c0 + 4 * j + 1][r],
                          Kf[c0 + 4 * j + 2][r], Kf[c0 + 4 * j + 3][r]);
        unsigned char* dst = Vps + ((size_t)(2 * tile + (c0 >> 5))) * 2048 + r * 32 + (c0 & 31);
        *reinterpret_cast<uint4*>(dst) = make_uint4(pw[0], pw[1], pw[2], pw[3]);
    }
    if (t < 64) {   // column partial sums (f32, exact keys)
        float s = 0.f;
        #pragma unroll 8
        for (int rr = 0; rr < 64; ++rr) s += Kf[rr][t];
        csum[((size_t)side * NTIL + tile) * 64 + t] = s;
    }
}

// grid (64, 2), block 64
__global__ __launch_bounds__(64) void sreduceA_kernel(const float* __restrict__ csum,
                                                      float* __restrict__ csum2)
{
    const int j = blockIdx.x, side = blockIdx.y, d = threadIdx.x;
    float s = 0.f;
    for (int idx = j; idx < NTIL; idx += 64)
        s += csum[((size_t)side * NTIL + idx) * 64 + d];
    csum2[((size_t)side * 64 + j) * 64 + d] = s;
}

// grid (2), block 64
__global__ __launch_bounds__(64) void sreduceB_kernel(const float* __restrict__ csum2,
                                                      float* __restrict__ Sbuf)
{
    const int side = blockIdx.x, d = threadIdx.x;
    float s = 0.f;
    #pragma unroll 8
    for (int j = 0; j < 64; ++j) s += csum2[((size_t)side * 64 + j) * 64 + d];
    Sbuf[side * 64 + d] = s;
}

// ---------------------------------------------------------------------------
// flash (MX-fp8): block = 8 waves (512 thr), each wave a 32-query tile; block
//   covers 256 q over one n-chunk of 1600 keys, 25 phases of 64 n.
// Per phase per wave: 2 QK mfma_scale_32x32x64 (st = n-half, K=64 = full d),
//   32 exp2, 16 cvt_pk_fp8 + 4 permlane32_swap (P A-frag), 2 PV mfma_scale
//   (dblk = d-half, K=64 = full phase-n), 8 ds_read_b128, 1 DMA issue.
// LDS per buffer (8KB, bytes): K: st*2048 + qh*1024 + hi*512 + c*16
//     holds K[st*32+c][d = 32hi + 16qh + 0..15]
//   V: 4096 + dblk*2048 + qh*1024 + hi*512 + c*16
//     holds V[n = 32hi + 16qh + 0..15][d = 32dblk + c]
// Operand maps (consistent believed bijection; cancels in A.B):
//   A/B lane (hi,c): row/col = c, k = 32hi + byte j (8 u32, j = 4w+b).
// C/D (verified, shape-determined): col = lane&31, row = (rr&3)+8(rr>>2)+4hi.
// P shuffle: p0[g],p1[g] = fp8x4 of s_st[4g..4g+3] (j = 8g+4hi+0..3 of st);
//   permswap(p0[g],p1[g]) -> lane hi holds full st=hi row: pa[2g]=p0[g],
//   pa[2g+1]=p1[g].
// Staging: wave w: dest = buf + w*1024 + lane*16; src K (w<4: st=w>>1, qh=w&1):
//   st*2048 + qh*16 + c*64 + hi*32; src V (w>=4: dblk=(w-4)>>1):
//   dblk*1024 + qh*16 + hi*2048 + c*32. Advance 4096 B/phase. Double-buffered,
//   DMA one full phase ahead, pre-barrier vmcnt(0) waits phase-old loads only.
// grid (NCH, 8, 2) = 1024 blocks.
// ---------------------------------------------------------------------------
__global__ __launch_bounds__(512) void flash_kernel(
    const float* __restrict__ user_emb, const float* __restrict__ item_emb,
    const int* __restrict__ user_id, const int* __restrict__ item_id,
    const unsigned char* __restrict__ Khid, const unsigned char* __restrict__ Vpan,
    unsigned short* __restrict__ Opart, float* __restrict__ lpart)
{
    const int side  = blockIdx.z;
    const int chunk = blockIdx.x;
    const int qblk  = blockIdx.y;
    const int wave  = threadIdx.x >> 6;
    const int lane  = threadIdx.x & 63;
    const int c  = lane & 31;
    const int hi = lane >> 5;

    __shared__ __align__(16) unsigned char KV[2][8192];   // 2 x 8KB

    const float* emb = (side == 0) ? user_emb : item_emb;
    const int* ids   = (side == 0) ? user_id  : item_id;
    const unsigned char* Kh = Khid + ((size_t)side * NP + (size_t)chunk * CHROWS) * 64;
    const unsigned char* Vb = Vpan + ((size_t)side * (NP / 32) + (size_t)chunk * (CHROWS / 32)) * 2048;

    // ---- staging setup: wave w stages LDS bytes [w*1024, w*1024+1024) per phase
    const unsigned char* gsrc;
    if (wave < 4) {
        const int st = wave >> 1, qh = wave & 1;
        gsrc = Kh + st * 2048 + qh * 16 + c * 64 + hi * 32;
    } else {
        const int dblk = (wave - 4) >> 1, qh = wave & 1;
        gsrc = Vb + dblk * 1024 + qh * 16 + hi * 2048 + c * 32;
    }

    const unsigned char* gnext = gsrc;      // source cursor for next ISSUE
    int ibuf = 0;                           // LDS buffer for next ISSUE
    auto ISSUE = [&]() {
        gl_lds16(gnext, &KV[ibuf][wave * 1024]);
        gnext += 4096;
        ibuf ^= 1;
    };

    // ---- Q gather (32 floats/lane: d = 32hi .. 32hi+31)
    const int qtile = qblk * 256 + wave * 32;
    const int id = ids[qtile + c];
    const float* qrow = emb + (size_t)id * 64 + hi * 32;
    float4 qf[8];
    #pragma unroll
    for (int w = 0; w < 8; ++w)
        qf[w] = *reinterpret_cast<const float4*>(qrow + w * 4);

    ISSUE();            // phase 0 -> buf 0

    // pack Q fp8 (B-operand of swapped QK^T), scaled by log2(e)
    i32x8 bq;
    #pragma unroll
    for (int w = 0; w < 8; ++w)
        bq[w] = (int)fp8x4(qf[w].x * LOG2E, qf[w].y * LOG2E,
                           qf[w].z * LOG2E, qf[w].w * LOG2E);

    f32x16 o0{}, o1{};
    f32x4 lsv{};

    asm volatile("s_waitcnt vmcnt(0)" ::: "memory");   // phase-0 DMA done
    __builtin_amdgcn_s_barrier();

    for (int p = 0; p < NPH; ++p) {
        if (p + 1 < NPH) ISSUE();

        const unsigned char* Bp = &KV[p & 1][0];
        const int fo = hi * 512 + c * 16;

        // K A-frags (2 st), 2 x b128 each
        i32x8 ak0 = cat8(*reinterpret_cast<const i32x4*>(Bp + fo),
                         *reinterpret_cast<const i32x4*>(Bp + 1024 + fo));
        i32x8 ak1 = cat8(*reinterpret_cast<const i32x4*>(Bp + 2048 + fo),
                         *reinterpret_cast<const i32x4*>(Bp + 3072 + fo));

        __builtin_amdgcn_s_setprio(1);
        f32x16 z{};
        f32x16 s0 = mfma8(ak0, bq, z);     // st0: n = 0..31
        f32x16 s1 = mfma8(ak1, bq, z);     // st1: n = 32..63
        __builtin_amdgcn_s_setprio(0);

        // V B-frags (2 dblk)
        i32x8 bv0 = cat8(*reinterpret_cast<const i32x4*>(Bp + 4096 + fo),
                         *reinterpret_cast<const i32x4*>(Bp + 5120 + fo));
        i32x8 bv1 = cat8(*reinterpret_cast<const i32x4*>(Bp + 6144 + fo),
                         *reinterpret_cast<const i32x4*>(Bp + 7168 + fo));

        // P = exp2(S); l accumulate (f32, exact)
        #pragma unroll
        for (int rr = 0; rr < 16; ++rr) s0[rr] = __builtin_exp2f(s0[rr]);
        #pragma unroll
        for (int rr = 0; rr < 16; ++rr) s1[rr] = __builtin_exp2f(s1[rr]);
        #pragma unroll
        for (int rr = 0; rr < 16; ++rr) lsv[rr & 3] += s0[rr] + s1[rr];

        // P fp8 A-frag via cvt_pk_fp8 + permlane32_swap
        unsigned int p0[4], p1[4];
        #pragma unroll
        for (int g = 0; g < 4; ++g) {
            p0[g] = fp8x4(s0[4 * g], s0[4 * g + 1], s0[4 * g + 2], s0[4 * g + 3]);
            p1[g] = fp8x4(s1[4 * g], s1[4 * g + 1], s1[4 * g + 2], s1[4 * g + 3]);
            permswap(p0[g], p1[g]);
        }
        i32x8 pa;
        pa[0] = (int)p0[0]; pa[1] = (int)p1[0];
        pa[2] = (int)p0[1]; pa[3] = (int)p1[1];
        pa[4] = (int)p0[2]; pa[5] = (int)p1[2];
        pa[6] = (int)p0[3]; pa[7] = (int)p1[3];

        __builtin_amdgcn_s_setprio(1);
        o0 = mfma8(pa, bv0, o0);           // d = 0..31
        o1 = mfma8(pa, bv1, o1);           // d = 32..63
        __builtin_amdgcn_s_setprio(0);

        if (p + 1 < NPH) {
            // own DMA for p+1 was issued a full phase ago -> near-free wait
            asm volatile("s_waitcnt vmcnt(0)" ::: "memory");
            __builtin_amdgcn_s_barrier();
        }
    }

    float ls = lsv[0] + lsv[1] + lsv[2] + lsv[3];
    ls += __shfl_xor(ls, 32);   // lane c now holds l[qtile+c] for this chunk

    unsigned short* Op = Opart + (((size_t)(side * NCH + chunk)) * BQ + qtile) * 64;
    #pragma unroll
    for (int rr = 0; rr < 16; ++rr) {
        const int q = (rr & 3) + 8 * (rr >> 2) + 4 * hi;
        Op[q * 64 + c]      = bfr(o0[rr]);
        Op[q * 64 + 32 + c] = bfr(o1[rr]);
    }
    if (hi == 0)
        lpart[((size_t)(side * NCH + chunk)) * BQ + qtile + c] = ls;
}

// ---------------------------------------------------------------------------
// combine: O = sum(Opart)/(sum(lpart) - PADCNT); q2 = e + O;
//          out = leaky_relu((q2+S)@W1^T + (q2*S)@W2^T); og = [e, out]
// grid (2*BQ), block 64
// ---------------------------------------------------------------------------
__global__ __launch_bounds__(64) void combine_kernel(
    const float* __restrict__ user_emb, const float* __restrict__ item_emb,
    const int* __restrict__ user_id, const int* __restrict__ item_id,
    const float* __restrict__ uW1, const float* __restrict__ uW2,
    const float* __restrict__ iW1, const float* __restrict__ iW2,
    const unsigned short* __restrict__ Opart, const float* __restrict__ lpart,
    const float* __restrict__ Sbuf,
    float* __restrict__ Aog, float* __restrict__ Bog)
{
    const int bid  = blockIdx.x;
    const int side = bid >> 11;
    const int q    = bid & (BQ - 1);
    const int d    = threadIdx.x;

    const unsigned short* Ob = Opart + ((size_t)side * NCH * BQ + q) * 64 + d;
    float num = 0.f;
    #pragma unroll 8
    for (int ch = 0; ch < NCH; ++ch)
        num += bf2f(Ob[(size_t)ch * BQ * 64]);
    const float* lb = lpart + (size_t)side * NCH * BQ + q;
    float lsum = -PADCNT;
    #pragma unroll 8
    for (int ch = 0; ch < NCH; ++ch)
        lsum += lb[(size_t)ch * BQ];

    const int id = ((side == 0) ? user_id : item_id)[q];
    const float* emb = (side == 0) ? user_emb : item_emb;
    const float e  = emb[(size_t)id * 64 + d];
    const float q2 = e + num / lsum;
    const float Sd = Sbuf[side * 64 + d];

    __shared__ float a1[64], a2[64];
    a1[d] = q2 + Sd;
    a2[d] = q2 * Sd;
    __syncthreads();

    const float* W1 = (side == 0) ? uW1 : iW1;
    const float* W2 = (side == 0) ? uW2 : iW2;
    float acc = 0.f;
    #pragma unroll 8
    for (int dd = 0; dd < 64; ++dd)
        acc += a1[dd] * W1[d * 64 + dd] + a2[dd] * W2[d * 64 + dd];
    const float out = (acc >= 0.f) ? acc : 0.01f * acc;

    float* og = (side == 0) ? Aog : Bog;
    og[(size_t)q * 128 + d]      = e;
    og[(size_t)q * 128 + 64 + d] = out;
}

// final stage 1: grid 32, block 256; block b: t-rows [64b, 64b+64), LDS-tiled,
// partial[b][i][j] = sum_t Aog[t][i]*Bog[t][j]
__global__ __launch_bounds__(256) void final1_kernel(
    const float* __restrict__ Aog, const float* __restrict__ Bog, float* __restrict__ part)
{
    const int b = blockIdx.x;
    const int t = threadIdx.x;
    __shared__ float As[64][128];
    __shared__ float Bs[64][128];
    {
        float* Asf = &As[0][0];
        float* Bsf = &Bs[0][0];
        const float* Ab = Aog + (size_t)b * 64 * 128;
        const float* Bb = Bog + (size_t)b * 64 * 128;
        #pragma unroll
        for (int qq = 0; qq < 8; ++qq) {
            const int off = qq * 1024 + t * 4;
            *reinterpret_cast<float4*>(Asf + off) = *reinterpret_cast<const float4*>(Ab + off);
            *reinterpret_cast<float4*>(Bsf + off) = *reinterpret_cast<const float4*>(Bb + off);
        }
    }
    __syncthreads();

    const int i0 = (t >> 4) * 8, j0 = (t & 15) * 8;
    float acc[8][8] = {};
    for (int k = 0; k < 64; ++k) {
        float av[8], bv[8];
        *reinterpret_cast<f32x4*>(&av[0]) = *reinterpret_cast<const f32x4*>(&As[k][i0]);
        *reinterpret_cast<f32x4*>(&av[4]) = *reinterpret_cast<const f32x4*>(&As[k][i0 + 4]);
        *reinterpret_cast<f32x4*>(&bv[0]) = *reinterpret_cast<const f32x4*>(&Bs[k][j0]);
        *reinterpret_cast<f32x4*>(&bv[4]) = *reinterpret_cast<const f32x4*>(&Bs[k][j0 + 4]);
        #pragma unroll
        for (int ii = 0; ii < 8; ++ii)
            #pragma unroll
            for (int jj = 0; jj < 8; ++jj)
                acc[ii][jj] += av[ii] * bv[jj];
    }
    float* P = part + (size_t)b * 128 * 128;
    #pragma unroll
    for (int ii = 0; ii < 8; ++ii) {
        *reinterpret_cast<float4*>(P + (i0 + ii) * 128 + j0)     = *reinterpret_cast<float4*>(&acc[ii][0]);
        *reinterpret_cast<float4*>(P + (i0 + ii) * 128 + j0 + 4) = *reinterpret_cast<float4*>(&acc[ii][4]);
    }
}

// final stage 2: grid 128, block 128: out[i][j] = sum_b partial[b][i][j]
__global__ __launch_bounds__(128) void final2_kernel(const float* __restrict__ part,
                                                     float* __restrict__ out)
{
    const int i = blockIdx.x, j = threadIdx.x;
    float s = 0.f;
    #pragma unroll 8
    for (int b = 0; b < 32; ++b) s += part[(size_t)b * 128 * 128 + i * 128 + j];
    out[i * 128 + j] = s;
}

extern "C" void kernel_launch(void* const* d_in, const int* in_sizes, int n_in,
                              void* d_out, int out_size, void* d_ws, size_t ws_size,
                              hipStream_t stream)
{
    (void)in_sizes; (void)n_in; (void)out_size; (void)ws_size;
    const float* user_emb = (const float*)d_in[0];
    const float* item_emb = (const float*)d_in[1];
    const float* uaW = (const float*)d_in[2];
    const float* uab = (const float*)d_in[3];
    const float* uW1 = (const float*)d_in[4];
    const float* uW2 = (const float*)d_in[5];
    const float* iaW = (const float*)d_in[6];
    const float* iab = (const float*)d_in[7];
    const float* iW1 = (const float*)d_in[8];
    const float* iW2 = (const float*)d_in[9];
    const int* user_id = (const int*)d_in[10];
    const int* item_id = (const int*)d_in[11];
    // d_in[12], d_in[13]: arange identity gathers -- no-ops.

    char* ws = (char*)d_ws;
    size_t off = 0;
    auto alloc = [&](size_t bytes) -> void* {
        void* p = ws + off;
        off = (off + bytes + 255) & ~(size_t)255;
        return p;
    };
    unsigned char* Khid8 = (unsigned char*)alloc((size_t)2 * NP * DIM);
    unsigned char* Vpan8 = (unsigned char*)alloc((size_t)2 * (NP / 32) * 2048);
    float* csum  = (float*)alloc((size_t)2 * NTIL * 64 * 4);
    float* csum2 = (float*)alloc((size_t)2 * 64 * 64 * 4);
    float* Sbuf  = (float*)alloc((size_t)2 * 64 * 4);
    unsigned short* Opart = (unsigned short*)alloc((size_t)2 * NCH * BQ * 64 * 2);
    float* lpart = (float*)alloc((size_t)2 * NCH * BQ * 4);
    float* Aog   = (float*)alloc((size_t)BQ * 128 * 4);
    float* Bog   = (float*)alloc((size_t)BQ * 128 * 4);
    float* Fpart = (float*)alloc((size_t)32 * 128 * 128 * 4);

    prep_kernel<<<dim3(NTIL, 2), 256, 0, stream>>>(user_emb, item_emb, uaW, uab, iaW, iab,
                                                   Khid8, Vpan8, csum);
    sreduceA_kernel<<<dim3(64, 2), 64, 0, stream>>>(csum, csum2);
    sreduceB_kernel<<<2, 64, 0, stream>>>(csum2, Sbuf);
    flash_kernel<<<dim3(NCH, BQ / 256, 2), 512, 0, stream>>>(user_emb, item_emb, user_id, item_id,
                                                             Khid8, Vpan8, Opart, lpart);
    combine_kernel<<<2 * BQ, 64, 0, stream>>>(user_emb, item_emb, user_id, item_id,
                                              uW1, uW2, iW1, iW2, Opart, lpart, Sbuf, Aog, Bog);
    final1_kernel<<<32, 256, 0, stream>>>(Aog, Bog, Fpart);
    final2_kernel<<<128, 128, 0, stream>>>(Fpart, (float*)d_out);
}

// Round 12
// 147.269 us; speedup vs baseline: 1.5752x; 1.2611x over previous
//
#include <hip/hip_runtime.h>

// ANCF recommender on MI355X.
// prep (MFMA hidden -> Khid fp8; keys^T -> Vpan fp8 n-panels; colsum partials)
//  -> sreduceA/B (S = colsum, 2-stage tree)
//  -> flash (streaming softmax attention, MX-fp8 mfma_scale 32x32x64 (scales=1.0):
//            2 QK MFMA + 2 PV MFMA + 8 ds_read_b128 per wave-phase.
//            Softmax VALU minimized: Schraudolph fast-exp2 (fma+cvt, +-3% rel,
//            fine vs fp8's 6% quantization; pads contribute fexp2(0) exactly,
//            matched in combine) and v_pk_add_f32 packed l-accumulation.
//            K/V staged via global_load_lds, double-buffered 2x8KB, 1 DMA/wave/
//            phase issued one full phase ahead; raw s_barrier. 8-wave blocks.)
//  -> combine (O/l, q2, epilogue (q2+S)W1^T+(q2*S)W2^T, leaky_relu, build og)
//  -> final1/2 (128x128 = og_user^T @ og_item, LDS-tiled, 32-way k-split)
// Workspace required: ~70 MB.

typedef __bf16 bf16x8 __attribute__((ext_vector_type(8)));
typedef float f32x2 __attribute__((ext_vector_type(2)));
typedef float f32x4 __attribute__((ext_vector_type(4)));
typedef float f32x16 __attribute__((ext_vector_type(16)));
typedef unsigned int u32x4 __attribute__((ext_vector_type(4)));
typedef int i32x4 __attribute__((ext_vector_type(4)));
typedef int i32x8 __attribute__((ext_vector_type(8)));

static constexpr int NKEYS  = 100000;
static constexpr int NP     = 102400;          // 64 chunks * 1600 rows
static constexpr int DIM    = 64;
static constexpr int BQ     = 2048;
static constexpr int NCH    = 64;
static constexpr int CHROWS = NP / NCH;        // 1600
static constexpr int NPH    = CHROWS / 64;     // 25 phases of 64 n
static constexpr int NTIL   = NP / 64;         // 1600
static constexpr float PADCNT = float(NP - NKEYS);   // 2400 pads, each adds fexp2(0) to l
static constexpr float LOG2E  = 1.44269504088896340736f;

#define DEVINL __device__ __forceinline__

DEVINL unsigned int cvtpk(float lo, float hi) {
    unsigned int r;
    asm("v_cvt_pk_bf16_f32 %0, %1, %2" : "=v"(r) : "v"(lo), "v"(hi));
    return r;
}
DEVINL unsigned short bfr(float f) {           // single f32 -> bf16 (RNE)
    return (unsigned short)(cvtpk(f, f) & 0xffffu);
}
DEVINL float bf2f(unsigned short u) {
    unsigned int w = (unsigned int)u << 16;
    return __builtin_bit_cast(float, w);
}
DEVINL void permswap(unsigned int& a, unsigned int& b) {
    asm("v_permlane32_swap_b32 %0, %1" : "+v"(a), "+v"(b));
}
DEVINL bf16x8 pack_frag(unsigned int w0, unsigned int w1, unsigned int w2, unsigned int w3) {
    u32x4 t; t[0] = w0; t[1] = w1; t[2] = w2; t[3] = w3;
    return __builtin_bit_cast(bf16x8, t);
}
DEVINL bf16x8 frag8_f32(const float* p) {      // 8 consecutive f32 -> bf16x8 frag
    f32x4 a = *reinterpret_cast<const f32x4*>(p);
    f32x4 b = *reinterpret_cast<const f32x4*>(p + 4);
    return pack_frag(cvtpk(a[0], a[1]), cvtpk(a[2], a[3]),
                     cvtpk(b[0], b[1]), cvtpk(b[2], b[3]));
}
// fp8 e4m3 helpers
DEVINL unsigned int fp8x4(float a, float b, float c, float d) {
    int r = __builtin_amdgcn_cvt_pk_fp8_f32(a, b, 0, false);   // bytes 0,1
    r = __builtin_amdgcn_cvt_pk_fp8_f32(c, d, r, true);        // bytes 2,3
    return (unsigned int)r;
}
DEVINL unsigned char fp8b(float f) {
    return (unsigned char)(__builtin_amdgcn_cvt_pk_fp8_f32(f, f, 0, false) & 0xFF);
}
DEVINL i32x8 cat8(i32x4 a, i32x4 b) {
    return __builtin_shufflevector(a, b, 0, 1, 2, 3, 4, 5, 6, 7);
}
// fp8 e4m3 MFMA, K=64, scales = 1.0 (e8m0 = 127 in every byte)
DEVINL f32x16 mfma8(i32x8 a, i32x8 b, f32x16 c) {
    return __builtin_amdgcn_mfma_scale_f32_32x32x64_f8f6f4(
        a, b, c, 0 /*cbsz: fp8*/, 0 /*blgp: fp8*/,
        0, 0x7F7F7F7F, 0, 0x7F7F7F7F);
}
// Schraudolph fast 2^x: linear-mantissa, max rel err ~+-3% (P is fp8 downstream,
// 6% quantization -- approx error is sub-dominant and mean-centered).
// Monotone; x=0 (pad rows) yields the exact constant bitcast((int)1065713994.f)
// at BOTH compile- and run-time (fma with x=0 returns the constant operand).
DEVINL float fexp2(float x) {
    float f = __builtin_fmaf(x, 8388608.0f, 1065713994.0f);   // 2^23, 127*2^23 + 0.043*2^23
    int i = (int)f;
    return __builtin_bit_cast(float, i);
}
// packed f32 add (v_pk_add_f32, CDNA2+): 2 adds in one instruction
DEVINL f32x2 pkadd(f32x2 a, f32x2 b) {
    f32x2 r;
    asm("v_pk_add_f32 %0, %1, %2" : "=v"(r) : "v"(a), "v"(b));
    return r;
}

// ---------------------------------------------------------------------------
// prep: per 64-row tile: hidden = relu(K @ aW^T + b) via 32x32x16 bf16 MFMA
//       -> Khid fp8 [n][64]; K^T -> Vpan fp8 (panels: Vpan[n/32][64 d][32 nn],
//       each panel 2KB contiguous); column-sum partials (f32, exact).
//       Pad rows (n >= NKEYS) exact zeros.
// grid (NTIL, 2), block 256
// ---------------------------------------------------------------------------
__global__ __launch_bounds__(256) void prep_kernel(
    const float* __restrict__ user_emb, const float* __restrict__ item_emb,
    const float* __restrict__ uaW, const float* __restrict__ uab,
    const float* __restrict__ iaW, const float* __restrict__ iab,
    unsigned char* __restrict__ Khid, unsigned char* __restrict__ Vpan,
    float* __restrict__ csum)
{
    const int side = blockIdx.y;
    const int tile = blockIdx.x;
    const float* keys = (side == 0) ? item_emb : user_emb;
    const float* aW   = (side == 0) ? uaW : iaW;
    const float* ab   = (side == 0) ? uab : iab;
    unsigned char* Kh  = Khid + (size_t)side * NP * DIM;
    unsigned char* Vps = Vpan + (size_t)side * (NP / 32) * 2048;

    __shared__ float Kf[64][68];
    __shared__ float Wf[64][68];
    __shared__ float bl[64];

    const int t  = threadIdx.x;
    const int r  = t >> 2;
    const int c0 = (t & 3) * 16;

    {   // stage aW rows (f32)
        const float4* src = reinterpret_cast<const float4*>(aW + r * 64 + c0);
        float4* dst = reinterpret_cast<float4*>(&Wf[r][c0]);
        #pragma unroll
        for (int q = 0; q < 4; ++q) dst[q] = src[q];
        if (t < 64) bl[t] = ab[t];
    }
    {   // stage keys tile (zero pads)
        const int n = tile * 64 + r;
        float4* dst = reinterpret_cast<float4*>(&Kf[r][c0]);
        if (n < NKEYS) {
            const float4* src = reinterpret_cast<const float4*>(keys + (size_t)n * 64 + c0);
            #pragma unroll
            for (int q = 0; q < 4; ++q) dst[q] = src[q];
        } else {
            const float4 z = make_float4(0.f, 0.f, 0.f, 0.f);
            #pragma unroll
            for (int q = 0; q < 4; ++q) dst[q] = z;
        }
    }
    __syncthreads();

    {   // hidden 32x32 tile per wave via bf16 MFMA
        const int wv = t >> 6, lane = t & 63;
        const int c = lane & 31, hi = lane >> 5;
        const int n0 = (wv & 1) * 32, j0 = (wv >> 1) * 32;
        f32x16 acc{};
        #pragma unroll
        for (int ks = 0; ks < 4; ++ks) {
            bf16x8 af = frag8_f32(&Kf[n0 + c][ks * 16 + hi * 8]);
            bf16x8 bf_ = frag8_f32(&Wf[j0 + c][ks * 16 + hi * 8]);
            acc = __builtin_amdgcn_mfma_f32_32x32x16_bf16(af, bf_, acc, 0, 0, 0);
        }
        const float bj = bl[j0 + c];
        #pragma unroll
        for (int rr = 0; rr < 16; ++rr) {
            const int n  = n0 + (rr & 3) + 8 * (rr >> 2) + 4 * hi;
            const int gn = tile * 64 + n;
            float h = fmaxf(acc[rr] + bj, 0.f);
            if (gn >= NKEYS) h = 0.f;
            Kh[(size_t)gn * 64 + j0 + c] = fp8b(h);
        }
    }
    {   // Vpan fp8: thread: d = r, nn-cols c0..c0+15 within this 64-tile
        unsigned int pw[4];
        #pragma unroll
        for (int j = 0; j < 4; ++j)
            pw[j] = fp8x4(Kf[c0 + 4 * j][r],     Kf[c0 + 4 * j + 1][r],
                          Kf[c0 + 4 * j + 2][r], Kf[c0 + 4 * j + 3][r]);
        unsigned char* dst = Vps + ((size_t)(2 * tile + (c0 >> 5))) * 2048 + r * 32 + (c0 & 31);
        *reinterpret_cast<uint4*>(dst) = make_uint4(pw[0], pw[1], pw[2], pw[3]);
    }
    if (t < 64) {   // column partial sums (f32, exact keys)
        float s = 0.f;
        #pragma unroll 8
        for (int rr = 0; rr < 64; ++rr) s += Kf[rr][t];
        csum[((size_t)side * NTIL + tile) * 64 + t] = s;
    }
}

// grid (64, 2), block 64
__global__ __launch_bounds__(64) void sreduceA_kernel(const float* __restrict__ csum,
                                                      float* __restrict__ csum2)
{
    const int j = blockIdx.x, side = blockIdx.y, d = threadIdx.x;
    float s = 0.f;
    for (int idx = j; idx < NTIL; idx += 64)
        s += csum[((size_t)side * NTIL + idx) * 64 + d];
    csum2[((size_t)side * 64 + j) * 64 + d] = s;
}

// grid (2), block 64
__global__ __launch_bounds__(64) void sreduceB_kernel(const float* __restrict__ csum2,
                                                      float* __restrict__ Sbuf)
{
    const int side = blockIdx.x, d = threadIdx.x;
    float s = 0.f;
    #pragma unroll 8
    for (int j = 0; j < 64; ++j) s += csum2[((size_t)side * 64 + j) * 64 + d];
    Sbuf[side * 64 + d] = s;
}

// ---------------------------------------------------------------------------
// flash (MX-fp8): block = 8 waves (512 thr), each wave a 32-query tile; block
//   covers 256 q over one n-chunk of 1600 keys, 25 phases of 64 n.
// Per phase per wave: 2 QK mfma_scale_32x32x64 (st = n-half, K=64 = full d),
//   32 fexp2 (fma+cvt), 16 pk_add (l), 16 cvt_pk_fp8 + 4 permlane32_swap,
//   2 PV mfma_scale (dblk = d-half, K=64 = full phase-n), 8 ds_read_b128, 1 DMA.
// LDS per buffer (8KB, bytes): K: st*2048 + qh*1024 + hi*512 + c*16
//     holds K[st*32+c][d = 32hi + 16qh + 0..15]
//   V: 4096 + dblk*2048 + qh*1024 + hi*512 + c*16
//     holds V[n = 32hi + 16qh + 0..15][d = 32dblk + c]
// A/B lane (hi,c): row/col = c, k = 32hi + byte j. C/D: col = lane&31,
//   row = (rr&3)+8(rr>>2)+4hi (verified, shape-determined).
// P shuffle: p0[g],p1[g] = fp8x4 of s{0,1}[4g..4g+3]; permswap -> lane hi holds
//   full st=hi row: pa[2g]=p0[g], pa[2g+1]=p1[g].
// Staging: wave w: dest = buf + w*1024 + lane*16; src K (w<4: st=w>>1, qh=w&1):
//   st*2048 + qh*16 + c*64 + hi*32; src V (w>=4: dblk=(w-4)>>1):
//   dblk*1024 + qh*16 + hi*2048 + c*32. Advance 4096 B/phase. Double-buffered,
//   DMA one full phase ahead, pre-barrier vmcnt(0) waits phase-old loads only.
// grid (NCH, 8, 2) = 1024 blocks.
// ---------------------------------------------------------------------------
__global__ __launch_bounds__(512) void flash_kernel(
    const float* __restrict__ user_emb, const float* __restrict__ item_emb,
    const int* __restrict__ user_id, const int* __restrict__ item_id,
    const unsigned char* __restrict__ Khid, const unsigned char* __restrict__ Vpan,
    unsigned short* __restrict__ Opart, float* __restrict__ lpart)
{
    const int side  = blockIdx.z;
    const int chunk = blockIdx.x;
    const int qblk  = blockIdx.y;
    const int wave  = threadIdx.x >> 6;
    const int lane  = threadIdx.x & 63;
    const int c  = lane & 31;
    const int hi = lane >> 5;

    __shared__ __align__(16) unsigned char KV[2][8192];   // 2 x 8KB

    const float* emb = (side == 0) ? user_emb : item_emb;
    const int* ids   = (side == 0) ? user_id  : item_id;
    const unsigned char* Kh = Khid + ((size_t)side * NP + (size_t)chunk * CHROWS) * 64;
    const unsigned char* Vb = Vpan + ((size_t)side * (NP / 32) + (size_t)chunk * (CHROWS / 32)) * 2048;

    // ---- staging setup: wave w stages LDS bytes [w*1024, w*1024+1024) per phase
    const unsigned char* gsrc;
    if (wave < 4) {
        const int st = wave >> 1, qh = wave & 1;
        gsrc = Kh + st * 2048 + qh * 16 + c * 64 + hi * 32;
    } else {
        const int dblk = (wave - 4) >> 1, qh = wave & 1;
        gsrc = Vb + dblk * 1024 + qh * 16 + hi * 2048 + c * 32;
    }

    const unsigned char* gnext = gsrc;      // source cursor for next ISSUE
    int ibuf = 0;                           // LDS buffer for next ISSUE
    auto ISSUE = [&]() {
        __builtin_amdgcn_global_load_lds(
            (const __attribute__((address_space(1))) unsigned int*)gnext,
            (__attribute__((address_space(3))) unsigned int*)&KV[ibuf][wave * 1024],
            16, 0, 0);
        gnext += 4096;
        ibuf ^= 1;
    };

    // ---- Q gather (32 floats/lane: d = 32hi .. 32hi+31)
    const int qtile = qblk * 256 + wave * 32;
    const int id = ids[qtile + c];
    const float* qrow = emb + (size_t)id * 64 + hi * 32;
    float4 qf[8];
    #pragma unroll
    for (int w = 0; w < 8; ++w)
        qf[w] = *reinterpret_cast<const float4*>(qrow + w * 4);

    ISSUE();            // phase 0 -> buf 0

    // pack Q fp8 (B-operand of swapped QK^T), scaled by log2(e)
    i32x8 bq;
    #pragma unroll
    for (int w = 0; w < 8; ++w)
        bq[w] = (int)fp8x4(qf[w].x * LOG2E, qf[w].y * LOG2E,
                           qf[w].z * LOG2E, qf[w].w * LOG2E);

    f32x16 o0{}, o1{};
    f32x2 lacc[8] = {};

    asm volatile("s_waitcnt vmcnt(0)" ::: "memory");   // phase-0 DMA done
    __builtin_amdgcn_s_barrier();

    for (int p = 0; p < NPH; ++p) {
        if (p + 1 < NPH) ISSUE();

        const unsigned char* Bp = &KV[p & 1][0];
        const int fo = hi * 512 + c * 16;

        // K A-frags (2 st), 2 x b128 each
        i32x8 ak0 = cat8(*reinterpret_cast<const i32x4*>(Bp + fo),
                         *reinterpret_cast<const i32x4*>(Bp + 1024 + fo));
        i32x8 ak1 = cat8(*reinterpret_cast<const i32x4*>(Bp + 2048 + fo),
                         *reinterpret_cast<const i32x4*>(Bp + 3072 + fo));

        __builtin_amdgcn_s_setprio(1);
        f32x16 z{};
        f32x16 s0 = mfma8(ak0, bq, z);     // st0: n = 0..31
        f32x16 s1 = mfma8(ak1, bq, z);     // st1: n = 32..63
        __builtin_amdgcn_s_setprio(0);

        // V B-frags (2 dblk)
        i32x8 bv0 = cat8(*reinterpret_cast<const i32x4*>(Bp + 4096 + fo),
                         *reinterpret_cast<const i32x4*>(Bp + 5120 + fo));
        i32x8 bv1 = cat8(*reinterpret_cast<const i32x4*>(Bp + 6144 + fo),
                         *reinterpret_cast<const i32x4*>(Bp + 7168 + fo));

        // P = fexp2(S) (fast exp2: fma + cvt, per element)
        #pragma unroll
        for (int rr = 0; rr < 16; ++rr) s0[rr] = fexp2(s0[rr]);
        #pragma unroll
        for (int rr = 0; rr < 16; ++rr) s1[rr] = fexp2(s1[rr]);

        // l accumulate via packed f32 adds
        #pragma unroll
        for (int g = 0; g < 8; ++g) {
            f32x2 a; a[0] = s0[2 * g]; a[1] = s0[2 * g + 1];
            f32x2 b; b[0] = s1[2 * g]; b[1] = s1[2 * g + 1];
            lacc[g] = pkadd(lacc[g], pkadd(a, b));
        }

        // P fp8 A-frag via cvt_pk_fp8 + permlane32_swap
        unsigned int p0[4], p1[4];
        #pragma unroll
        for (int g = 0; g < 4; ++g) {
            p0[g] = fp8x4(s0[4 * g], s0[4 * g + 1], s0[4 * g + 2], s0[4 * g + 3]);
            p1[g] = fp8x4(s1[4 * g], s1[4 * g + 1], s1[4 * g + 2], s1[4 * g + 3]);
            permswap(p0[g], p1[g]);
        }
        i32x8 pa;
        pa[0] = (int)p0[0]; pa[1] = (int)p1[0];
        pa[2] = (int)p0[1]; pa[3] = (int)p1[1];
        pa[4] = (int)p0[2]; pa[5] = (int)p1[2];
        pa[6] = (int)p0[3]; pa[7] = (int)p1[3];

        __builtin_amdgcn_s_setprio(1);
        o0 = mfma8(pa, bv0, o0);           // d = 0..31
        o1 = mfma8(pa, bv1, o1);           // d = 32..63
        __builtin_amdgcn_s_setprio(0);

        if (p + 1 < NPH) {
            // own DMA for p+1 was issued a full phase ago -> near-free wait
            asm volatile("s_waitcnt vmcnt(0)" ::: "memory");
            __builtin_amdgcn_s_barrier();
        }
    }

    float ls = 0.f;
    #pragma unroll
    for (int g = 0; g < 8; ++g) ls += lacc[g][0] + lacc[g][1];
    ls += __shfl_xor(ls, 32);   // lane c now holds l[qtile+c] for this chunk

    unsigned short* Op = Opart + (((size_t)(side * NCH + chunk)) * BQ + qtile) * 64;
    #pragma unroll
    for (int rr = 0; rr < 16; ++rr) {
        const int q = (rr & 3) + 8 * (rr >> 2) + 4 * hi;
        Op[q * 64 + c]      = bfr(o0[rr]);
        Op[q * 64 + 32 + c] = bfr(o1[rr]);
    }
    if (hi == 0)
        lpart[((size_t)(side * NCH + chunk)) * BQ + qtile + c] = ls;
}

// ---------------------------------------------------------------------------
// combine: O = sum(Opart)/(sum(lpart) - PADCNT*fexp2(0)); q2 = e + O;
//          out = leaky_relu((q2+S)@W1^T + (q2*S)@W2^T); og = [e, out]
// grid (2*BQ), block 64
// ---------------------------------------------------------------------------
__global__ __launch_bounds__(64) void combine_kernel(
    const float* __restrict__ user_emb, const float* __restrict__ item_emb,
    const int* __restrict__ user_id, const int* __restrict__ item_id,
    const float* __restrict__ uW1, const float* __restrict__ uW2,
    const float* __restrict__ iW1, const float* __restrict__ iW2,
    const unsigned short* __restrict__ Opart, const float* __restrict__ lpart,
    const float* __restrict__ Sbuf,
    float* __restrict__ Aog, float* __restrict__ Bog)
{
    const int bid  = blockIdx.x;
    const int side = bid >> 11;
    const int q    = bid & (BQ - 1);
    const int d    = threadIdx.x;

    const unsigned short* Ob = Opart + ((size_t)side * NCH * BQ + q) * 64 + d;
    float num = 0.f;
    #pragma unroll 8
    for (int ch = 0; ch < NCH; ++ch)
        num += bf2f(Ob[(size_t)ch * BQ * 64]);
    const float* lb = lpart + (size_t)side * NCH * BQ + q;
    // each pad key contributed exactly fexp2(0) to l (same instruction sequence)
    float lsum = -PADCNT * fexp2(0.0f);
    #pragma unroll 8
    for (int ch = 0; ch < NCH; ++ch)
        lsum += lb[(size_t)ch * BQ];

    const int id = ((side == 0) ? user_id : item_id)[q];
    const float* emb = (side == 0) ? user_emb : item_emb;
    const float e  = emb[(size_t)id * 64 + d];
    const float q2 = e + num / lsum;
    const float Sd = Sbuf[side * 64 + d];

    __shared__ float a1[64], a2[64];
    a1[d] = q2 + Sd;
    a2[d] = q2 * Sd;
    __syncthreads();

    const float* W1 = (side == 0) ? uW1 : iW1;
    const float* W2 = (side == 0) ? uW2 : iW2;
    float acc = 0.f;
    #pragma unroll 8
    for (int dd = 0; dd < 64; ++dd)
        acc += a1[dd] * W1[d * 64 + dd] + a2[dd] * W2[d * 64 + dd];
    const float out = (acc >= 0.f) ? acc : 0.01f * acc;

    float* og = (side == 0) ? Aog : Bog;
    og[(size_t)q * 128 + d]      = e;
    og[(size_t)q * 128 + 64 + d] = out;
}

// final stage 1: grid 32, block 256; block b: t-rows [64b, 64b+64), LDS-tiled,
// partial[b][i][j] = sum_t Aog[t][i]*Bog[t][j]
__global__ __launch_bounds__(256) void final1_kernel(
    const float* __restrict__ Aog, const float* __restrict__ Bog, float* __restrict__ part)
{
    const int b = blockIdx.x;
    const int t = threadIdx.x;
    __shared__ float As[64][128];
    __shared__ float Bs[64][128];
    {
        float* Asf = &As[0][0];
        float* Bsf = &Bs[0][0];
        const float* Ab = Aog + (size_t)b * 64 * 128;
        const float* Bb = Bog + (size_t)b * 64 * 128;
        #pragma unroll
        for (int qq = 0; qq < 8; ++qq) {
            const int off = qq * 1024 + t * 4;
            *reinterpret_cast<float4*>(Asf + off) = *reinterpret_cast<const float4*>(Ab + off);
            *reinterpret_cast<float4*>(Bsf + off) = *reinterpret_cast<const float4*>(Bb + off);
        }
    }
    __syncthreads();

    const int i0 = (t >> 4) * 8, j0 = (t & 15) * 8;
    float acc[8][8] = {};
    for (int k = 0; k < 64; ++k) {
        float av[8], bv[8];
        *reinterpret_cast<f32x4*>(&av[0]) = *reinterpret_cast<const f32x4*>(&As[k][i0]);
        *reinterpret_cast<f32x4*>(&av[4]) = *reinterpret_cast<const f32x4*>(&As[k][i0 + 4]);
        *reinterpret_cast<f32x4*>(&bv[0]) = *reinterpret_cast<const f32x4*>(&Bs[k][j0]);
        *reinterpret_cast<f32x4*>(&bv[4]) = *reinterpret_cast<const f32x4*>(&Bs[k][j0 + 4]);
        #pragma unroll
        for (int ii = 0; ii < 8; ++ii)
            #pragma unroll
            for (int jj = 0; jj < 8; ++jj)
                acc[ii][jj] += av[ii] * bv[jj];
    }
    float* P = part + (size_t)b * 128 * 128;
    #pragma unroll
    for (int ii = 0; ii < 8; ++ii) {
        *reinterpret_cast<float4*>(P + (i0 + ii) * 128 + j0)     = *reinterpret_cast<float4*>(&acc[ii][0]);
        *reinterpret_cast<float4*>(P + (i0 + ii) * 128 + j0 + 4) = *reinterpret_cast<float4*>(&acc[ii][4]);
    }
}

// final stage 2: grid 128, block 128: out[i][j] = sum_b partial[b][i][j]
__global__ __launch_bounds__(128) void final2_kernel(const float* __restrict__ part,
                                                     float* __restrict__ out)
{
    const int i = blockIdx.x, j = threadIdx.x;
    float s = 0.f;
    #pragma unroll 8
    for (int b = 0; b < 32; ++b) s += part[(size_t)b * 128 * 128 + i * 128 + j];
    out[i * 128 + j] = s;
}

extern "C" void kernel_launch(void* const* d_in, const int* in_sizes, int n_in,
                              void* d_out, int out_size, void* d_ws, size_t ws_size,
                              hipStream_t stream)
{
    (void)in_sizes; (void)n_in; (void)out_size; (void)ws_size;
    const float* user_emb = (const float*)d_in[0];
    const float* item_emb = (const float*)d_in[1];
    const float* uaW = (const float*)d_in[2];
    const float* uab = (const float*)d_in[3];
    const float* uW1 = (const float*)d_in[4];
    const float* uW2 = (const float*)d_in[5];
    const float* iaW = (const float*)d_in[6];
    const float* iab = (const float*)d_in[7];
    const float* iW1 = (const float*)d_in[8];
    const float* iW2 = (const float*)d_in[9];
    const int* user_id = (const int*)d_in[10];
    const int* item_id = (const int*)d_in[11];
    // d_in[12], d_in[13]: arange identity gathers -- no-ops.

    char* ws = (char*)d_ws;
    size_t off = 0;
    auto alloc = [&](size_t bytes) -> void* {
        void* p = ws + off;
        off = (off + bytes + 255) & ~(size_t)255;
        return p;
    };
    unsigned char* Khid8 = (unsigned char*)alloc((size_t)2 * NP * DIM);
    unsigned char* Vpan8 = (unsigned char*)alloc((size_t)2 * (NP / 32) * 2048);
    float* csum  = (float*)alloc((size_t)2 * NTIL * 64 * 4);
    float* csum2 = (float*)alloc((size_t)2 * 64 * 64 * 4);
    float* Sbuf  = (float*)alloc((size_t)2 * 64 * 4);
    unsigned short* Opart = (unsigned short*)alloc((size_t)2 * NCH * BQ * 64 * 2);
    float* lpart = (float*)alloc((size_t)2 * NCH * BQ * 4);
    float* Aog   = (float*)alloc((size_t)BQ * 128 * 4);
    float* Bog   = (float*)alloc((size_t)BQ * 128 * 4);
    float* Fpart = (float*)alloc((size_t)32 * 128 * 128 * 4);

    prep_kernel<<<dim3(NTIL, 2), 256, 0, stream>>>(user_emb, item_emb, uaW, uab, iaW, iab,
                                                   Khid8, Vpan8, csum);
    sreduceA_kernel<<<dim3(64, 2), 64, 0, stream>>>(csum, csum2);
    sreduceB_kernel<<<2, 64, 0, stream>>>(csum2, Sbuf);
    flash_kernel<<<dim3(NCH, BQ / 256, 2), 512, 0, stream>>>(user_emb, item_emb, user_id, item_id,
                                                             Khid8, Vpan8, Opart, lpart);
    combine_kernel<<<2 * BQ, 64, 0, stream>>>(user_emb, item_emb, user_id, item_id,
                                              uW1, uW2, iW1, iW2, Opart, lpart, Sbuf, Aog, Bog);
    final1_kernel<<<32, 256, 0, stream>>>(Aog, Bog, Fpart);
    final2_kernel<<<128, 128, 0, stream>>>(Fpart, (float*)d_out);
}